// Round 1
// baseline (962.243 us; speedup 1.0000x reference)
//
#include <hip/hip_runtime.h>
#include <hip/hip_bf16.h>
#include <math.h>

// GRUCell with adaptive-graph GCN on MI355X (gfx950).
// B=64, N=2048, Din=2, H=64, D=16, C=66, O=64.
// Pipeline: e -> A(bf16) -> X^T(bf16) -> [per gate] MFMA GEMM Y=A@xs -> per-node einsum.
// Big GEMM in bf16 MFMA (no fp32 MFMA on CDNA4); all reductions accumulate fp32.

typedef __attribute__((ext_vector_type(4))) float f4;
typedef __attribute__((ext_vector_type(8))) short s8;  // 8 bf16 in 4 VGPRs (MFMA A/B frag)

#define B_   64
#define N_   2048
#define DIN  2
#define H_   64
#define D_   16
#define C_   66    // DIN + H
#define KI   132   // 2*C
#define CB   4224  // B_*C_

// ---------------------------------------------------------------- e = LN(node+time)*gamma+beta
__global__ void k_e(const float* __restrict__ node, const float* __restrict__ timee,
                    const float* __restrict__ g0, const float* __restrict__ b0,
                    const float* __restrict__ g1, const float* __restrict__ b1,
                    const float* __restrict__ g2, const float* __restrict__ b2,
                    float* __restrict__ e) {
  int n = blockIdx.x * blockDim.x + threadIdx.x;
  if (n >= N_) return;
  float v[D_]; float m = 0.f;
  #pragma unroll
  for (int d = 0; d < D_; ++d) { v[d] = node[n * D_ + d] + timee[d]; m += v[d]; }
  m *= (1.0f / D_);
  float var = 0.f;
  #pragma unroll
  for (int d = 0; d < D_; ++d) { float t = v[d] - m; var += t * t; }
  var *= (1.0f / D_);
  float r = rsqrtf(var + 1e-12f);
  #pragma unroll
  for (int d = 0; d < D_; ++d) {
    float y = (v[d] - m) * r;
    e[0 * N_ * D_ + n * D_ + d] = y * g0[d] + b0[d];
    e[1 * N_ * D_ + n * D_ + d] = y * g1[d] + b1[d];
    e[2 * N_ * D_ + n * D_ + d] = y * g2[d] + b2[d];
  }
}

// ---------------------------------------------------------------- A_g = softmax(e_g e_g^T, axis=1), bf16
__global__ void k_softmaxA(const float* __restrict__ e, __hip_bfloat16* __restrict__ A) {
  int g = blockIdx.y, n = blockIdx.x, t = threadIdx.x;
  const float* eg = e + (size_t)g * N_ * D_;
  __shared__ float en[D_];
  __shared__ float red[256];
  if (t < D_) en[t] = eg[n * D_ + t];
  __syncthreads();
  float s[8]; float lmax = -1e30f;
  for (int j = 0; j < 8; ++j) {
    int m = j * 256 + t;
    float acc = 0.f;
    #pragma unroll
    for (int d = 0; d < D_; ++d) acc += en[d] * eg[m * D_ + d];
    s[j] = acc; lmax = fmaxf(lmax, acc);
  }
  red[t] = lmax; __syncthreads();
  for (int st = 128; st > 0; st >>= 1) { if (t < st) red[t] = fmaxf(red[t], red[t + st]); __syncthreads(); }
  float gmax = red[0]; __syncthreads();
  float lsum = 0.f;
  for (int j = 0; j < 8; ++j) { s[j] = __expf(s[j] - gmax); lsum += s[j]; }
  red[t] = lsum; __syncthreads();
  for (int st = 128; st > 0; st >>= 1) { if (t < st) red[t] += red[t + st]; __syncthreads(); }
  float inv = 1.0f / red[0];
  __hip_bfloat16* An = A + (size_t)g * N_ * N_ + (size_t)n * N_;
  for (int j = 0; j < 8; ++j) An[j * 256 + t] = __float2bfloat16(s[j] * inv);
}

// ---------------------------------------------------------------- X^T[j=b*C+c][m] bf16 (K-contiguous for GEMM B-operand)
template <int MODE>  // 0: xs=[x,state]   1: cand=[x, z*state]
__global__ void k_buildX(const float* __restrict__ x, const float* __restrict__ state,
                         const __hip_bfloat16* __restrict__ zbuf, __hip_bfloat16* __restrict__ XT) {
  int idx = blockIdx.x * 256 + threadIdx.x;   // 4224*2048 total, exact
  int j = idx >> 11; int m = idx & 2047;
  int b = j / C_; int c = j - b * C_;
  float v;
  if (c < DIN) {
    v = x[((size_t)b * N_ + m) * DIN + c];
  } else {
    size_t si = ((size_t)b * N_ + m) * H_ + (c - DIN);
    v = state[si];
    if (MODE) v *= __bfloat162float(zbuf[si]);
  }
  XT[(size_t)j * N_ + m] = __float2bfloat16(v);
}

// ---------------------------------------------------------------- Y[r,j] = sum_m A[r,m] XT[j,m]  (bf16 MFMA, fp32 acc -> bf16)
__global__ __launch_bounds__(256)
void k_gemm(const __hip_bfloat16* __restrict__ Ag, const __hip_bfloat16* __restrict__ XT,
            __hip_bfloat16* __restrict__ Y) {
  constexpr int LD = 40;  // padded row stride (shorts): breaks 64B-row bank aliasing on frag reads
  __shared__ __align__(16) short At[128 * LD];
  __shared__ __align__(16) short Xt[128 * LD];
  int t = threadIdx.x;
  int j0 = blockIdx.x * 128, r0 = blockIdx.y * 128;
  int rs = t >> 1, h = t & 1;                 // staging: thread = (row, 16-elem half)
  const ushort* Ap = (const ushort*)Ag + (size_t)(r0 + rs) * N_ + h * 16;
  const ushort* Xp = (const ushort*)XT + (size_t)(j0 + rs) * N_ + h * 16;
  int lane15 = t & 15, q = (t >> 4) & 3, wv = t >> 6;
  int wr = (wv >> 1) * 64, wc = (wv & 1) * 64;
  f4 acc[4][4];
  #pragma unroll
  for (int i = 0; i < 4; ++i)
    #pragma unroll
    for (int jj = 0; jj < 4; ++jj) acc[i][jj] = (f4)0.0f;
  short* sa = &At[rs * LD + h * 16];
  short* sx = &Xt[rs * LD + h * 16];
  for (int k0 = 0; k0 < N_; k0 += 32) {
    __syncthreads();
    uint4 va0 = ((const uint4*)(Ap + k0))[0];
    uint4 va1 = ((const uint4*)(Ap + k0))[1];
    uint4 vx0 = ((const uint4*)(Xp + k0))[0];
    uint4 vx1 = ((const uint4*)(Xp + k0))[1];
    ((uint4*)sa)[0] = va0; ((uint4*)sa)[1] = va1;
    ((uint4*)sx)[0] = vx0; ((uint4*)sx)[1] = vx1;
    __syncthreads();
    s8 af[4], bf[4];
    #pragma unroll
    for (int mi = 0; mi < 4; ++mi) af[mi] = *(const s8*)&At[(wr + mi * 16 + lane15) * LD + q * 8];
    #pragma unroll
    for (int ni = 0; ni < 4; ++ni) bf[ni] = *(const s8*)&Xt[(wc + ni * 16 + lane15) * LD + q * 8];
    #pragma unroll
    for (int mi = 0; mi < 4; ++mi)
      #pragma unroll
      for (int ni = 0; ni < 4; ++ni)
        acc[mi][ni] = __builtin_amdgcn_mfma_f32_16x16x32_bf16(af[mi], bf[ni], acc[mi][ni], 0, 0, 0);
  }
  // C/D: col = lane&15, row = quad*4 + reg  [verified m89/m91]
  #pragma unroll
  for (int mi = 0; mi < 4; ++mi) {
    int rr = r0 + wr + mi * 16 + q * 4;
    #pragma unroll
    for (int ni = 0; ni < 4; ++ni) {
      int cc = j0 + wc + ni * 16 + lane15;
      #pragma unroll
      for (int rg = 0; rg < 4; ++rg)
        Y[(size_t)(rr + rg) * CB + cc] = __float2bfloat16(acc[mi][ni][rg]);
    }
  }
}

// ---------------------------------------------------------------- per-node einsum + epilogue
// out[b,o] = bias[o] + sum_ki xg[b,ki] * W_n[ki,o],  W_n[ki,o] = sum_d e[n,d] Wp[d,ki,o]
template <int MODE>  // 0: sigmoid -> bf16 gate buf ; 1: tanh + GRU combine -> fp32 d_out
__global__ __launch_bounds__(256)
void k_einsum(const float* __restrict__ e, const float* __restrict__ Wp, const float* __restrict__ bp,
              const __hip_bfloat16* __restrict__ Y,
              const float* __restrict__ x, const float* __restrict__ state,
              const __hip_bfloat16* __restrict__ zbuf, const __hip_bfloat16* __restrict__ rbuf,
              void* __restrict__ outp) {
  int n = blockIdx.x, t = threadIdx.x;
  __shared__ float Wl[KI * 64];              // 33792 B
  __shared__ __hip_bfloat16 xg[64 * 134];    // 17152 B, stride 134 -> conflict-free per-lane reads
  __shared__ float el[D_];
  __shared__ float bl[64];
  if (t < D_) el[t] = e[n * D_ + t];
  __syncthreads();
  for (int idx = t; idx < KI * 64; idx += 256) {
    float s = 0.f;
    #pragma unroll
    for (int d = 0; d < D_; ++d) s += el[d] * Wp[d * (KI * 64) + idx];
    Wl[idx] = s;
  }
  if (t < 64) {
    float s = 0.f;
    #pragma unroll
    for (int d = 0; d < D_; ++d) s += el[d] * bp[d * 64 + t];
    bl[t] = s;
  }
  for (int idx = t; idx < 64 * KI; idx += 256) {
    int b = idx / KI; int i = idx - b * KI;
    float v;
    if (i >= C_) {
      v = __bfloat162float(Y[(size_t)n * CB + b * C_ + (i - C_)]);
    } else if (i >= DIN) {
      size_t si = ((size_t)b * N_ + n) * H_ + (i - DIN);
      v = state[si];
      if (MODE) v *= __bfloat162float(zbuf[si]);
    } else {
      v = x[((size_t)b * N_ + n) * DIN + i];
    }
    xg[b * 134 + i] = __float2bfloat16(v);
  }
  __syncthreads();
  int lane = t & 63, wvv = t >> 6;  // lane = b, wave = o-group of 16
  f4 a0 = (f4)0.f, a1 = (f4)0.f, a2 = (f4)0.f, a3 = (f4)0.f;
  const __hip_bfloat16* xr = &xg[lane * 134];
  #pragma unroll 4
  for (int i = 0; i < KI; ++i) {
    float xv = __bfloat162float(xr[i]);            // 2-way banked: free
    const f4* wp4 = (const f4*)&Wl[i * 64 + wvv * 16];  // wave-uniform: LDS broadcast
    a0 += xv * wp4[0]; a1 += xv * wp4[1]; a2 += xv * wp4[2]; a3 += xv * wp4[3];
  }
  float res[16];
  *(f4*)&res[0] = a0; *(f4*)&res[4] = a1; *(f4*)&res[8] = a2; *(f4*)&res[12] = a3;
  size_t base = ((size_t)lane * N_ + n) * 64 + wvv * 16;
  if (MODE == 0) {
    __hip_bfloat16* ob = (__hip_bfloat16*)outp;
    #pragma unroll
    for (int oo = 0; oo < 16; ++oo) {
      float v = res[oo] + bl[wvv * 16 + oo];
      ob[base + oo] = __float2bfloat16(1.0f / (1.0f + __expf(-v)));
    }
  } else {
    float* ob = (float*)outp;
    #pragma unroll
    for (int oo = 0; oo < 16; ++oo) {
      float v = res[oo] + bl[wvv * 16 + oo];
      float hc = tanhf(v);
      float rv = __bfloat162float(rbuf[base + oo]);
      float st = state[base + oo];
      ob[base + oo] = rv * st + (1.0f - rv) * hc;
    }
  }
}

// ----------------------------------------------------------------
extern "C" void kernel_launch(void* const* d_in, const int* in_sizes, int n_in,
                              void* d_out, int out_size, void* d_ws, size_t ws_size,
                              hipStream_t stream) {
  const float* x     = (const float*)d_in[0];
  const float* state = (const float*)d_in[1];
  const float* node  = (const float*)d_in[2];
  const float* timee = (const float*)d_in[3];
  const float* W_z = (const float*)d_in[4];
  const float* b_z = (const float*)d_in[5];
  const float* g_z = (const float*)d_in[6];
  const float* be_z = (const float*)d_in[7];
  const float* W_r = (const float*)d_in[8];
  const float* b_r = (const float*)d_in[9];
  const float* g_r = (const float*)d_in[10];
  const float* be_r = (const float*)d_in[11];
  const float* W_u = (const float*)d_in[12];
  const float* b_u = (const float*)d_in[13];
  const float* g_u = (const float*)d_in[14];
  const float* be_u = (const float*)d_in[15];

  constexpr size_t NN = (size_t)N_ * N_;     // per-gate A elements
  constexpr size_t ND = (size_t)N_ * D_;
  // Workspace layout (bytes), total ~93.7 MB:
  char* ws = (char*)d_ws;
  float*           e  = (float*)(ws);                        // 3*2048*16*4      = 393,216
  __hip_bfloat16*  A  = (__hip_bfloat16*)(ws + 393216);      // 3*2048*2048*2    = 25,165,824
  __hip_bfloat16*  XT = (__hip_bfloat16*)(ws + 25559040);    // 4224*2048*2      = 17,301,504 (reused for cand)
  __hip_bfloat16*  Y  = (__hip_bfloat16*)(ws + 42860544);    // 2048*4224*2      = 17,301,504 (reused per gate)
  __hip_bfloat16*  zb = (__hip_bfloat16*)(ws + 60162048);    // 64*2048*64*2     = 16,777,216
  __hip_bfloat16*  rb = (__hip_bfloat16*)(ws + 76939264);    // 16,777,216

  float* out = (float*)d_out;

  k_e<<<8, 256, 0, stream>>>(node, timee, g_z, be_z, g_r, be_r, g_u, be_u, e);
  k_softmaxA<<<dim3(N_, 3), 256, 0, stream>>>(e, A);
  k_buildX<0><<<(CB * N_) / 256, 256, 0, stream>>>(x, state, nullptr, XT);

  dim3 ggrid(CB / 128, N_ / 128);  // 33 x 16

  // gate z
  k_gemm<<<ggrid, 256, 0, stream>>>(A + 0 * NN, XT, Y);
  k_einsum<0><<<N_, 256, 0, stream>>>(e + 0 * ND, W_z, b_z, Y, x, state, nullptr, nullptr, (void*)zb);
  // gate r
  k_gemm<<<ggrid, 256, 0, stream>>>(A + 1 * NN, XT, Y);
  k_einsum<0><<<N_, 256, 0, stream>>>(e + 1 * ND, W_r, b_r, Y, x, state, nullptr, nullptr, (void*)rb);
  // gate u: cand = [x, z*state]
  k_buildX<1><<<(CB * N_) / 256, 256, 0, stream>>>(x, state, zb, XT);
  k_gemm<<<ggrid, 256, 0, stream>>>(A + 2 * NN, XT, Y);
  k_einsum<1><<<N_, 256, 0, stream>>>(e + 2 * ND, W_u, b_u, Y, x, state, zb, rb, (void*)out);
}

// Round 2
// 623.006 us; speedup vs baseline: 1.5445x; 1.5445x over previous
//
#include <hip/hip_runtime.h>
#include <hip/hip_bf16.h>
#include <math.h>

// GRUCell with adaptive-graph GCN on MI355X (gfx950).
// B=64, N=2048, Din=2, H=64, D=16, C=66, O=64.
// Pipeline: e -> A(bf16) -> X^T(bf16) -> [per gate] MFMA GEMM Y=A@xs -> per-node MFMA einsum.

typedef __attribute__((ext_vector_type(4))) float f4;
typedef __attribute__((ext_vector_type(8))) short s8;  // 8 bf16 in 4 VGPRs (MFMA A/B frag)

#define B_   64
#define N_   2048
#define DIN  2
#define H_   64
#define D_   16
#define C_   66    // DIN + H
#define KI   132   // 2*C
#define CB   4224  // B_*C_

static __device__ __forceinline__ ushort f2bf(float v) {
  __hip_bfloat16 h = __float2bfloat16(v);
  return *(ushort*)&h;
}
static __device__ __forceinline__ float bf2f(ushort u) {
  __hip_bfloat16 h = *(__hip_bfloat16*)&u;
  return __bfloat162float(h);
}

// ---------------------------------------------------------------- e = LN(node+time)*gamma+beta
__global__ void k_e(const float* __restrict__ node, const float* __restrict__ timee,
                    const float* __restrict__ g0, const float* __restrict__ b0,
                    const float* __restrict__ g1, const float* __restrict__ b1,
                    const float* __restrict__ g2, const float* __restrict__ b2,
                    float* __restrict__ e) {
  int n = blockIdx.x * blockDim.x + threadIdx.x;
  if (n >= N_) return;
  float v[D_]; float m = 0.f;
  #pragma unroll
  for (int d = 0; d < D_; ++d) { v[d] = node[n * D_ + d] + timee[d]; m += v[d]; }
  m *= (1.0f / D_);
  float var = 0.f;
  #pragma unroll
  for (int d = 0; d < D_; ++d) { float t = v[d] - m; var += t * t; }
  var *= (1.0f / D_);
  float r = rsqrtf(var + 1e-12f);
  #pragma unroll
  for (int d = 0; d < D_; ++d) {
    float y = (v[d] - m) * r;
    e[0 * N_ * D_ + n * D_ + d] = y * g0[d] + b0[d];
    e[1 * N_ * D_ + n * D_ + d] = y * g1[d] + b1[d];
    e[2 * N_ * D_ + n * D_ + d] = y * g2[d] + b2[d];
  }
}

// ---------------------------------------------------------------- A_g = softmax(e_g e_g^T, axis=1), bf16
__global__ void k_softmaxA(const float* __restrict__ e, __hip_bfloat16* __restrict__ A) {
  int g = blockIdx.y, n = blockIdx.x, t = threadIdx.x;
  const float* eg = e + (size_t)g * N_ * D_;
  __shared__ float en[D_];
  __shared__ float red[256];
  if (t < D_) en[t] = eg[n * D_ + t];
  __syncthreads();
  float s[8]; float lmax = -1e30f;
  for (int j = 0; j < 8; ++j) {
    int m = j * 256 + t;
    float acc = 0.f;
    #pragma unroll
    for (int d = 0; d < D_; ++d) acc += en[d] * eg[m * D_ + d];
    s[j] = acc; lmax = fmaxf(lmax, acc);
  }
  red[t] = lmax; __syncthreads();
  for (int st = 128; st > 0; st >>= 1) { if (t < st) red[t] = fmaxf(red[t], red[t + st]); __syncthreads(); }
  float gmax = red[0]; __syncthreads();
  float lsum = 0.f;
  for (int j = 0; j < 8; ++j) { s[j] = __expf(s[j] - gmax); lsum += s[j]; }
  red[t] = lsum; __syncthreads();
  for (int st = 128; st > 0; st >>= 1) { if (t < st) red[t] += red[t + st]; __syncthreads(); }
  float inv = 1.0f / red[0];
  __hip_bfloat16* An = A + (size_t)g * N_ * N_ + (size_t)n * N_;
  for (int j = 0; j < 8; ++j) An[j * 256 + t] = __float2bfloat16(s[j] * inv);
}

// ---------------------------------------------------------------- X^T[j=b*C+c][m] bf16 (K-contiguous for GEMM B-operand)
template <int MODE>  // 0: xs=[x,state]   1: cand=[x, z*state]
__global__ void k_buildX(const float* __restrict__ x, const float* __restrict__ state,
                         const __hip_bfloat16* __restrict__ zbuf, __hip_bfloat16* __restrict__ XT) {
  int idx = blockIdx.x * 256 + threadIdx.x;   // 4224*2048 total, exact
  int j = idx >> 11; int m = idx & 2047;
  int b = j / C_; int c = j - b * C_;
  float v;
  if (c < DIN) {
    v = x[((size_t)b * N_ + m) * DIN + c];
  } else {
    size_t si = ((size_t)b * N_ + m) * H_ + (c - DIN);
    v = state[si];
    if (MODE) v *= __bfloat162float(zbuf[si]);
  }
  XT[(size_t)j * N_ + m] = __float2bfloat16(v);
}

// ---------------------------------------------------------------- Y[r,j] = sum_m A[r,m] XT[j,m]  (bf16 MFMA, fp32 acc -> bf16)
__global__ __launch_bounds__(256)
void k_gemm(const __hip_bfloat16* __restrict__ Ag, const __hip_bfloat16* __restrict__ XT,
            __hip_bfloat16* __restrict__ Y) {
  constexpr int LD = 40;  // padded row stride (shorts): breaks 64B-row bank aliasing on frag reads
  __shared__ __align__(16) short At[128 * LD];
  __shared__ __align__(16) short Xt[128 * LD];
  int t = threadIdx.x;
  int j0 = blockIdx.x * 128, r0 = blockIdx.y * 128;
  int rs = t >> 1, h = t & 1;                 // staging: thread = (row, 16-elem half)
  const ushort* Ap = (const ushort*)Ag + (size_t)(r0 + rs) * N_ + h * 16;
  const ushort* Xp = (const ushort*)XT + (size_t)(j0 + rs) * N_ + h * 16;
  int lane15 = t & 15, q = (t >> 4) & 3, wv = t >> 6;
  int wr = (wv >> 1) * 64, wc = (wv & 1) * 64;
  f4 acc[4][4];
  #pragma unroll
  for (int i = 0; i < 4; ++i)
    #pragma unroll
    for (int jj = 0; jj < 4; ++jj) acc[i][jj] = (f4)0.0f;
  short* sa = &At[rs * LD + h * 16];
  short* sx = &Xt[rs * LD + h * 16];
  for (int k0 = 0; k0 < N_; k0 += 32) {
    __syncthreads();
    uint4 va0 = ((const uint4*)(Ap + k0))[0];
    uint4 va1 = ((const uint4*)(Ap + k0))[1];
    uint4 vx0 = ((const uint4*)(Xp + k0))[0];
    uint4 vx1 = ((const uint4*)(Xp + k0))[1];
    ((uint4*)sa)[0] = va0; ((uint4*)sa)[1] = va1;
    ((uint4*)sx)[0] = vx0; ((uint4*)sx)[1] = vx1;
    __syncthreads();
    s8 af[4], bf[4];
    #pragma unroll
    for (int mi = 0; mi < 4; ++mi) af[mi] = *(const s8*)&At[(wr + mi * 16 + lane15) * LD + q * 8];
    #pragma unroll
    for (int ni = 0; ni < 4; ++ni) bf[ni] = *(const s8*)&Xt[(wc + ni * 16 + lane15) * LD + q * 8];
    #pragma unroll
    for (int mi = 0; mi < 4; ++mi)
      #pragma unroll
      for (int ni = 0; ni < 4; ++ni)
        acc[mi][ni] = __builtin_amdgcn_mfma_f32_16x16x32_bf16(af[mi], bf[ni], acc[mi][ni], 0, 0, 0);
  }
  // C/D: col = lane&15, row = quad*4 + reg  [verified m89/m91]
  #pragma unroll
  for (int mi = 0; mi < 4; ++mi) {
    int rr = r0 + wr + mi * 16 + q * 4;
    #pragma unroll
    for (int ni = 0; ni < 4; ++ni) {
      int cc = j0 + wc + ni * 16 + lane15;
      #pragma unroll
      for (int rg = 0; rg < 4; ++rg)
        Y[(size_t)(rr + rg) * CB + cc] = __float2bfloat16(acc[mi][ni][rg]);
    }
  }
}

// ---------------------------------------------------------------- per-node einsum via MFMA
// out[b,o] = act( bias_n[o] + sum_ki xg[b,ki] * W_n[ki,o] ),  W_n[ki,o] = sum_d e[n,d] Wp[d,ki,o]
// Stage1: Wt[o][ki] (bf16, LDS).  Stage2: 64x64 tile, K=132 padded to 160, MFMA 16x16x32.
// Epilogue: activation in-register, transpose via LDS, coalesced global stores.
template <int MODE>  // 0: sigmoid -> bf16 gate buf ; 1: tanh + GRU combine -> fp32 d_out
__global__ __launch_bounds__(256, 3)
void k_einsum(const float* __restrict__ e, const float* __restrict__ Wp, const float* __restrict__ bp,
              const __hip_bfloat16* __restrict__ Y,
              const float* __restrict__ x, const float* __restrict__ state,
              const __hip_bfloat16* __restrict__ zbuf, const __hip_bfloat16* __restrict__ rbuf,
              void* __restrict__ outp) {
  constexpr int LDK = 168;  // row stride in shorts: 336B -> frag b128 reads spread over all 32 banks (<=2-way)
  constexpr int LDR = 72;
  __shared__ __align__(16) ushort Wt[64 * LDK];   // 21504 B : W_n^T  [o][ki]
  __shared__ __align__(16) ushort xg[64 * LDK];   // 21504 B : A tile [b][ki]
  __shared__ __align__(16) ushort res[64 * LDR];  //  9216 B : activated result [b][o]
  __shared__ float el[D_];
  __shared__ float bl[64];
  const int n = blockIdx.x, t = threadIdx.x;
  if (t < D_) el[t] = e[n * D_ + t];
  __syncthreads();
  float er[D_];
  #pragma unroll
  for (int d = 0; d < D_; ++d) er[d] = el[d];     // wave-uniform broadcast reads
  if (t < 64) {
    float s = 0.f;
    #pragma unroll
    for (int d = 0; d < D_; ++d) s += er[d] * bp[d * 64 + t];
    bl[t] = s;
  }
  const int o = t & 63, kq = t >> 6;
  // ---- stage 1: Wt[o][ki] = bf16( sum_d er[d] * Wp[d][ki][o] ); lanes consecutive in o -> coalesced
  {
    const float* wpo = Wp + o;
    for (int pass = 0; pass < 33; ++pass) {
      const int ki = pass * 4 + kq;
      const float* wp = wpo + (size_t)ki * 64;
      float a = 0.f;
      #pragma unroll
      for (int d = 0; d < D_; ++d) a = fmaf(er[d], wp[(size_t)d * (KI * 64)], a);
      Wt[o * LDK + ki] = f2bf(a);
    }
    // zero K-pad (ki 132..159)
    uint* pz = (uint*)&Wt[o * LDK + 132 + kq * 8];
    const int cz = (kq < 3) ? 4 : 2;
    for (int i = 0; i < cz; ++i) pz[i] = 0u;
  }
  // ---- build xg[b][ki] = [x(2) | state*(z?) (64) | Y row (66)], bf16, K-pad zeroed
  {
    const int b = t >> 2, j = t & 3;
    const size_t bn = (size_t)b * N_ + n;
    // state part -> ki 2..65
    float sv[16];
    const float* sp = state + bn * 64 + j * 16;
    #pragma unroll
    for (int i = 0; i < 16; i += 4) {
      float4 v = *(const float4*)(sp + i);
      sv[i] = v.x; sv[i + 1] = v.y; sv[i + 2] = v.z; sv[i + 3] = v.w;
    }
    if (MODE) {
      const ushort* zp = (const ushort*)zbuf + bn * 64 + j * 16;
      uint4 z0 = *(const uint4*)&zp[0], z1 = *(const uint4*)&zp[8];
      uint zw[8] = {z0.x, z0.y, z0.z, z0.w, z1.x, z1.y, z1.z, z1.w};
      #pragma unroll
      for (int i = 0; i < 8; ++i) {
        sv[2 * i]     *= bf2f((ushort)(zw[i] & 0xffffu));
        sv[2 * i + 1] *= bf2f((ushort)(zw[i] >> 16));
      }
    }
    ushort* xr = &xg[b * LDK + 2 + j * 16];
    #pragma unroll
    for (int i = 0; i < 16; i += 2) {
      uint pk = ((uint)f2bf(sv[i + 1]) << 16) | f2bf(sv[i]);
      *(uint*)&xr[i] = pk;
    }
    // Y part -> ki 66..131
    const ushort* yp = (const ushort*)Y + (size_t)n * CB + b * C_ + j * 16;
    uint* xy = (uint*)&xg[b * LDK + 66 + j * 16];
    #pragma unroll
    for (int i = 0; i < 8; ++i) xy[i] = *(const uint*)&yp[2 * i];
    if (j == 0) *(uint*)&xg[b * LDK + 130] = *(const uint*)&yp[64];
    // x part -> ki 0..1
    if (t < 64) {
      const float* xp = x + ((size_t)t * N_ + n) * DIN;
      uint pk = ((uint)f2bf(xp[1]) << 16) | f2bf(xp[0]);
      *(uint*)&xg[t * LDK] = pk;
    }
    // zero K-pad (ki 132..159), 7 shorts per thread-quarter
    ushort* pg = &xg[b * LDK + 132 + j * 7];
    #pragma unroll
    for (int i = 0; i < 7; ++i) pg[i] = 0;
  }
  __syncthreads();
  // ---- stage 2: MFMA 64x64, K=160
  const int l15 = t & 15, q = (t >> 4) & 3, w = t >> 6;
  const int wm = (w >> 1) * 32, wn = (w & 1) * 32;
  f4 acc[2][2];
  acc[0][0] = acc[0][1] = acc[1][0] = acc[1][1] = (f4)0.0f;
  #pragma unroll
  for (int kk = 0; kk < 160; kk += 32) {
    s8 af[2], bfr[2];
    #pragma unroll
    for (int mi = 0; mi < 2; ++mi) af[mi] = *(const s8*)&xg[(wm + mi * 16 + l15) * LDK + kk + q * 8];
    #pragma unroll
    for (int ni = 0; ni < 2; ++ni) bfr[ni] = *(const s8*)&Wt[(wn + ni * 16 + l15) * LDK + kk + q * 8];
    #pragma unroll
    for (int mi = 0; mi < 2; ++mi)
      #pragma unroll
      for (int ni = 0; ni < 2; ++ni)
        acc[mi][ni] = __builtin_amdgcn_mfma_f32_16x16x32_bf16(af[mi], bfr[ni], acc[mi][ni], 0, 0, 0);
  }
  // bias + activation in-register, stage to LDS transposed
  {
    float bl0 = bl[wn + l15], bl1 = bl[wn + 16 + l15];
    #pragma unroll
    for (int mi = 0; mi < 2; ++mi)
      #pragma unroll
      for (int ni = 0; ni < 2; ++ni) {
        float bb = ni ? bl1 : bl0;
        #pragma unroll
        for (int rg = 0; rg < 4; ++rg) {
          float v = acc[mi][ni][rg] + bb;
          float a;
          if (MODE == 0) a = 1.0f / (1.0f + __expf(-v));
          else           a = 1.0f - 2.0f / (__expf(2.0f * v) + 1.0f);  // tanh, saturates correctly
          res[(wm + mi * 16 + q * 4 + rg) * LDR + (wn + ni * 16 + l15)] = f2bf(a);
        }
      }
  }
  __syncthreads();
  // ---- epilogue: coalesced stores (4 lanes cover one b-row of 64 o's)
  {
    const int b = t >> 2, j = t & 3;
    const size_t gb = ((size_t)b * N_ + n) * 64 + j * 16;
    const ushort* rr = &res[b * LDR + j * 16];
    if (MODE == 0) {
      uint4 v0 = *(const uint4*)&rr[0];
      uint4 v1 = *(const uint4*)&rr[8];
      *(uint4*)((ushort*)outp + gb) = v0;
      *(uint4*)((ushort*)outp + gb + 8) = v1;
    } else {
      float* ob = (float*)outp;
      const float* stp = state + gb;
      const ushort* rp = (const ushort*)rbuf + gb;
      uint4 r0 = *(const uint4*)&rp[0], r1 = *(const uint4*)&rp[8];
      uint rw[8] = {r0.x, r0.y, r0.z, r0.w, r1.x, r1.y, r1.z, r1.w};
      #pragma unroll
      for (int i = 0; i < 16; i += 4) {
        float4 st = *(const float4*)(stp + i);
        float4 ov;
        float rv0 = bf2f((ushort)(rw[i / 2] & 0xffffu));
        float rv1 = bf2f((ushort)(rw[i / 2] >> 16));
        float rv2 = bf2f((ushort)(rw[i / 2 + 1] & 0xffffu));
        float rv3 = bf2f((ushort)(rw[i / 2 + 1] >> 16));
        ov.x = rv0 * st.x + (1.0f - rv0) * bf2f(rr[i]);
        ov.y = rv1 * st.y + (1.0f - rv1) * bf2f(rr[i + 1]);
        ov.z = rv2 * st.z + (1.0f - rv2) * bf2f(rr[i + 2]);
        ov.w = rv3 * st.w + (1.0f - rv3) * bf2f(rr[i + 3]);
        *(float4*)(ob + gb + i) = ov;
      }
    }
  }
}

// ----------------------------------------------------------------
extern "C" void kernel_launch(void* const* d_in, const int* in_sizes, int n_in,
                              void* d_out, int out_size, void* d_ws, size_t ws_size,
                              hipStream_t stream) {
  const float* x     = (const float*)d_in[0];
  const float* state = (const float*)d_in[1];
  const float* node  = (const float*)d_in[2];
  const float* timee = (const float*)d_in[3];
  const float* W_z = (const float*)d_in[4];
  const float* b_z = (const float*)d_in[5];
  const float* g_z = (const float*)d_in[6];
  const float* be_z = (const float*)d_in[7];
  const float* W_r = (const float*)d_in[8];
  const float* b_r = (const float*)d_in[9];
  const float* g_r = (const float*)d_in[10];
  const float* be_r = (const float*)d_in[11];
  const float* W_u = (const float*)d_in[12];
  const float* b_u = (const float*)d_in[13];
  const float* g_u = (const float*)d_in[14];
  const float* be_u = (const float*)d_in[15];

  constexpr size_t NN = (size_t)N_ * N_;     // per-gate A elements
  constexpr size_t ND = (size_t)N_ * D_;
  // Workspace layout (bytes), total ~93.7 MB:
  char* ws = (char*)d_ws;
  float*           e  = (float*)(ws);                        // 3*2048*16*4      = 393,216
  __hip_bfloat16*  A  = (__hip_bfloat16*)(ws + 393216);      // 3*2048*2048*2    = 25,165,824
  __hip_bfloat16*  XT = (__hip_bfloat16*)(ws + 25559040);    // 4224*2048*2      = 17,301,504 (reused for cand)
  __hip_bfloat16*  Y  = (__hip_bfloat16*)(ws + 42860544);    // 2048*4224*2      = 17,301,504 (reused per gate)
  __hip_bfloat16*  zb = (__hip_bfloat16*)(ws + 60162048);    // 64*2048*64*2     = 16,777,216
  __hip_bfloat16*  rb = (__hip_bfloat16*)(ws + 76939264);    // 16,777,216

  float* out = (float*)d_out;

  k_e<<<8, 256, 0, stream>>>(node, timee, g_z, be_z, g_r, be_r, g_u, be_u, e);
  k_softmaxA<<<dim3(N_, 3), 256, 0, stream>>>(e, A);
  k_buildX<0><<<(CB * N_) / 256, 256, 0, stream>>>(x, state, nullptr, XT);

  dim3 ggrid(CB / 128, N_ / 128);  // 33 x 16

  // gate z
  k_gemm<<<ggrid, 256, 0, stream>>>(A + 0 * NN, XT, Y);
  k_einsum<0><<<N_, 256, 0, stream>>>(e + 0 * ND, W_z, b_z, Y, x, state, nullptr, nullptr, (void*)zb);
  // gate r
  k_gemm<<<ggrid, 256, 0, stream>>>(A + 1 * NN, XT, Y);
  k_einsum<0><<<N_, 256, 0, stream>>>(e + 1 * ND, W_r, b_r, Y, x, state, nullptr, nullptr, (void*)rb);
  // gate u: cand = [x, z*state]
  k_buildX<1><<<(CB * N_) / 256, 256, 0, stream>>>(x, state, zb, XT);
  k_gemm<<<ggrid, 256, 0, stream>>>(A + 2 * NN, XT, Y);
  k_einsum<1><<<N_, 256, 0, stream>>>(e + 2 * ND, W_u, b_u, Y, x, state, zb, rb, (void*)out);
}

// Round 4
// 622.809 us; speedup vs baseline: 1.5450x; 1.0003x over previous
//
#include <hip/hip_runtime.h>
#include <hip/hip_bf16.h>
#include <math.h>

// GRUCell with adaptive-graph GCN on MI355X (gfx950).
// B=64, N=2048, Din=2, H=64, D=16, C=66, O=64.
// R4: R3 + fix k_buildX epilogue (was writing only 8 of 16 shorts per chunk).

typedef __attribute__((ext_vector_type(4))) float f4;
typedef __attribute__((ext_vector_type(8))) short s8;  // 8 bf16 in 4 VGPRs (MFMA A/B frag)

#define B_   64
#define N_   2048
#define DIN  2
#define H_   64
#define D_   16
#define C_   66    // DIN + H
#define KI   132   // 2*C
#define KIP  160   // KI padded for K-loop (multiple of 32)
#define CB   4224  // B_*C_

#define GLD16(gp, lp) __builtin_amdgcn_global_load_lds((const __attribute__((address_space(1))) void*)(gp), (__attribute__((address_space(3))) void*)(lp), 16, 0, 0)

static __device__ __forceinline__ ushort f2bf(float v) {
  __hip_bfloat16 h = __float2bfloat16(v);
  return *(ushort*)&h;
}
static __device__ __forceinline__ float bf2f(ushort u) {
  __hip_bfloat16 h = *(__hip_bfloat16*)&u;
  return __bfloat162float(h);
}

// ---------------------------------------------------------------- e = LN(node+time)*gamma+beta
__global__ void k_e(const float* __restrict__ node, const float* __restrict__ timee,
                    const float* __restrict__ g0, const float* __restrict__ b0,
                    const float* __restrict__ g1, const float* __restrict__ b1,
                    const float* __restrict__ g2, const float* __restrict__ b2,
                    float* __restrict__ e) {
  int n = blockIdx.x * blockDim.x + threadIdx.x;
  if (n >= N_) return;
  float v[D_]; float m = 0.f;
  #pragma unroll
  for (int d = 0; d < D_; ++d) { v[d] = node[n * D_ + d] + timee[d]; m += v[d]; }
  m *= (1.0f / D_);
  float var = 0.f;
  #pragma unroll
  for (int d = 0; d < D_; ++d) { float t = v[d] - m; var += t * t; }
  var *= (1.0f / D_);
  float r = rsqrtf(var + 1e-12f);
  #pragma unroll
  for (int d = 0; d < D_; ++d) {
    float y = (v[d] - m) * r;
    e[0 * N_ * D_ + n * D_ + d] = y * g0[d] + b0[d];
    e[1 * N_ * D_ + n * D_ + d] = y * g1[d] + b1[d];
    e[2 * N_ * D_ + n * D_ + d] = y * g2[d] + b2[d];
  }
}

// ---------------------------------------------------------------- S = e_g @ e_g^T (fp32 out), MFMA K=16 padded to 32
__global__ __launch_bounds__(256)
void k_S(const float* __restrict__ eg, float* __restrict__ S) {
  __shared__ __align__(16) ushort At[128 * 32];
  __shared__ __align__(16) ushort Bt[128 * 32];
  const int t = threadIdx.x;
  const int c0 = blockIdx.x * 128, r0 = blockIdx.y * 128;
  const int row = t >> 1, half = t & 1;
  {
    const float* p = eg + (size_t)(r0 + row) * D_ + half * 8;
    float4 a = *(const float4*)p, b = *(const float4*)(p + 4);
    ushort pk[8] = {f2bf(a.x), f2bf(a.y), f2bf(a.z), f2bf(a.w), f2bf(b.x), f2bf(b.y), f2bf(b.z), f2bf(b.w)};
    *(uint4*)&At[row * 32 + half * 8] = *(uint4*)pk;
    uint4 z = {0, 0, 0, 0};
    *(uint4*)&At[row * 32 + 16 + half * 8] = z;
    const float* q2 = eg + (size_t)(c0 + row) * D_ + half * 8;
    float4 c = *(const float4*)q2, d = *(const float4*)(q2 + 4);
    ushort pk2[8] = {f2bf(c.x), f2bf(c.y), f2bf(c.z), f2bf(c.w), f2bf(d.x), f2bf(d.y), f2bf(d.z), f2bf(d.w)};
    *(uint4*)&Bt[row * 32 + half * 8] = *(uint4*)pk2;
    *(uint4*)&Bt[row * 32 + 16 + half * 8] = z;
  }
  __syncthreads();
  const int l15 = t & 15, q = (t >> 4) & 3, w = t >> 6;
  const int wr = (w >> 1) * 64, wc = (w & 1) * 64;
  s8 af[4], bf[4];
  #pragma unroll
  for (int mi = 0; mi < 4; ++mi) af[mi] = *(const s8*)&At[(wr + mi * 16 + l15) * 32 + q * 8];
  #pragma unroll
  for (int ni = 0; ni < 4; ++ni) bf[ni] = *(const s8*)&Bt[(wc + ni * 16 + l15) * 32 + q * 8];
  f4 acc[4][4];
  #pragma unroll
  for (int i = 0; i < 4; ++i)
    #pragma unroll
    for (int j = 0; j < 4; ++j) acc[i][j] = (f4)0.0f;
  #pragma unroll
  for (int mi = 0; mi < 4; ++mi)
    #pragma unroll
    for (int ni = 0; ni < 4; ++ni)
      acc[mi][ni] = __builtin_amdgcn_mfma_f32_16x16x32_bf16(af[mi], bf[ni], acc[mi][ni], 0, 0, 0);
  #pragma unroll
  for (int mi = 0; mi < 4; ++mi) {
    int rr = r0 + wr + mi * 16 + q * 4;
    #pragma unroll
    for (int ni = 0; ni < 4; ++ni) {
      int cc = c0 + wc + ni * 16 + l15;
      #pragma unroll
      for (int rg = 0; rg < 4; ++rg)
        S[(size_t)(rr + rg) * N_ + cc] = acc[mi][ni][rg];
    }
  }
}

// ---------------------------------------------------------------- row softmax: A = softmax(S, axis=1), bf16
__global__ __launch_bounds__(256)
void k_rowsm(const float* __restrict__ S, __hip_bfloat16* __restrict__ A) {
  __shared__ float red[256];
  const int r = blockIdx.x, t = threadIdx.x;
  const float* Sr = S + (size_t)r * N_;
  float4 v0 = ((const float4*)Sr)[t];
  float4 v1 = ((const float4*)Sr)[t + 256];
  float mx = fmaxf(fmaxf(fmaxf(v0.x, v0.y), fmaxf(v0.z, v0.w)),
                   fmaxf(fmaxf(v1.x, v1.y), fmaxf(v1.z, v1.w)));
  red[t] = mx; __syncthreads();
  for (int st = 128; st > 0; st >>= 1) { if (t < st) red[t] = fmaxf(red[t], red[t + st]); __syncthreads(); }
  const float gmax = red[0]; __syncthreads();
  float e0 = __expf(v0.x - gmax), e1 = __expf(v0.y - gmax), e2 = __expf(v0.z - gmax), e3 = __expf(v0.w - gmax);
  float e4 = __expf(v1.x - gmax), e5 = __expf(v1.y - gmax), e6 = __expf(v1.z - gmax), e7 = __expf(v1.w - gmax);
  red[t] = e0 + e1 + e2 + e3 + e4 + e5 + e6 + e7; __syncthreads();
  for (int st = 128; st > 0; st >>= 1) { if (t < st) red[t] += red[t + st]; __syncthreads(); }
  const float inv = 1.0f / red[0];
  ushort* Ar = (ushort*)A + (size_t)r * N_;
  ushort p0[4] = {f2bf(e0 * inv), f2bf(e1 * inv), f2bf(e2 * inv), f2bf(e3 * inv)};
  ushort p1[4] = {f2bf(e4 * inv), f2bf(e5 * inv), f2bf(e6 * inv), f2bf(e7 * inv)};
  *(uint2*)&Ar[t * 4] = *(uint2*)p0;
  *(uint2*)&Ar[1024 + t * 4] = *(uint2*)p1;
}

// ---------------------------------------------------------------- X^T[j=b*C+c][m] bf16 via LDS transpose
template <int MODE>  // 0: xs=[x,state]   1: cand=[x, z*state]
__global__ __launch_bounds__(256)
void k_buildX(const float* __restrict__ x, const float* __restrict__ state,
              const __hip_bfloat16* __restrict__ zbuf, __hip_bfloat16* __restrict__ XT) {
  constexpr int LDM = 72;  // row stride (shorts), 144 B: 16B-aligned rows
  __shared__ __align__(16) ushort T[C_ * LDM];
  const int t = threadIdx.x;
  const int m0 = blockIdx.x * 64, b = blockIdx.y;
  const int m = t >> 2, hq = t & 3;
  {
    const float* sp = state + ((size_t)b * N_ + m0 + m) * H_ + hq * 16;
    float sv[16];
    #pragma unroll
    for (int i = 0; i < 16; i += 4) {
      float4 v = *(const float4*)(sp + i);
      sv[i] = v.x; sv[i + 1] = v.y; sv[i + 2] = v.z; sv[i + 3] = v.w;
    }
    if (MODE) {
      const ushort* zp = (const ushort*)zbuf + ((size_t)b * N_ + m0 + m) * H_ + hq * 16;
      uint4 z0 = *(const uint4*)&zp[0], z1 = *(const uint4*)&zp[8];
      uint zw[8] = {z0.x, z0.y, z0.z, z0.w, z1.x, z1.y, z1.z, z1.w};
      #pragma unroll
      for (int i = 0; i < 8; ++i) {
        sv[2 * i]     *= bf2f((ushort)(zw[i] & 0xffffu));
        sv[2 * i + 1] *= bf2f((ushort)(zw[i] >> 16));
      }
    }
    #pragma unroll
    for (int i = 0; i < 16; ++i) T[(DIN + hq * 16 + i) * LDM + m] = f2bf(sv[i]);
    if (t < 64) {
      const float2 xv = *(const float2*)&x[((size_t)b * N_ + m0 + t) * DIN];
      T[0 * LDM + t] = f2bf(xv.x);
      T[1 * LDM + t] = f2bf(xv.y);
    }
  }
  __syncthreads();
  {
    // each thread copies its full 16-short (32 B) chunk = two uint4s  [R4 fix]
    int r = t >> 2, ch = t & 3;
    ushort* dst = (ushort*)XT + (size_t)(b * C_ + r) * N_ + m0 + ch * 16;
    *(uint4*)&dst[0] = *(uint4*)&T[r * LDM + ch * 16];
    *(uint4*)&dst[8] = *(uint4*)&T[r * LDM + ch * 16 + 8];
    if (t < 8) {
      r = 64 + (t >> 2);
      ushort* dst2 = (ushort*)XT + (size_t)(b * C_ + r) * N_ + m0 + ch * 16;
      *(uint4*)&dst2[0] = *(uint4*)&T[r * LDM + ch * 16];
      *(uint4*)&dst2[8] = *(uint4*)&T[r * LDM + ch * 16 + 8];
    }
  }
}

// ---------------------------------------------------------------- Y[r,j] = sum_m A[r,m] XT[j,m]  (m97: global_load_lds staging)
__global__ __launch_bounds__(256)
void k_gemm(const __hip_bfloat16* __restrict__ Ag, const __hip_bfloat16* __restrict__ XT,
            __hip_bfloat16* __restrict__ Y) {
  __shared__ __align__(16) ushort At[128 * 32];
  __shared__ __align__(16) ushort Xt[128 * 32];
  const int t = threadIdx.x;
  const int j0 = blockIdx.x * 128, r0 = blockIdx.y * 128;
  const int lane = t & 63, w = t >> 6;
  const int rowa = w * 32 + (lane >> 2), kc = (lane & 3) * 8;
  const ushort* gA = (const ushort*)Ag + (size_t)(r0 + rowa) * N_ + kc;
  const ushort* gX = (const ushort*)XT + (size_t)(j0 + rowa) * N_ + kc;
  ushort* lA0 = &At[(w * 32) * 32];       // wave-uniform LDS bases; HW scatters lane*16B
  ushort* lA1 = &At[(w * 32 + 16) * 32];
  ushort* lX0 = &Xt[(w * 32) * 32];
  ushort* lX1 = &Xt[(w * 32 + 16) * 32];
  const int l15 = t & 15, q = (t >> 4) & 3;
  const int wr = (w >> 1) * 64, wc = (w & 1) * 64;
  f4 acc[4][4];
  #pragma unroll
  for (int i = 0; i < 4; ++i)
    #pragma unroll
    for (int jj = 0; jj < 4; ++jj) acc[i][jj] = (f4)0.0f;
  for (int k0 = 0; k0 < N_; k0 += 32) {
    __syncthreads();
    GLD16(gA + k0, lA0);
    GLD16(gA + 16 * N_ + k0, lA1);
    GLD16(gX + k0, lX0);
    GLD16(gX + 16 * N_ + k0, lX1);
    __syncthreads();   // compiler drains vmcnt(0) before s_barrier -> LDS data visible
    s8 af[4], bf[4];
    #pragma unroll
    for (int mi = 0; mi < 4; ++mi) af[mi] = *(const s8*)&At[(wr + mi * 16 + l15) * 32 + q * 8];
    #pragma unroll
    for (int ni = 0; ni < 4; ++ni) bf[ni] = *(const s8*)&Xt[(wc + ni * 16 + l15) * 32 + q * 8];
    #pragma unroll
    for (int mi = 0; mi < 4; ++mi)
      #pragma unroll
      for (int ni = 0; ni < 4; ++ni)
        acc[mi][ni] = __builtin_amdgcn_mfma_f32_16x16x32_bf16(af[mi], bf[ni], acc[mi][ni], 0, 0, 0);
  }
  // C/D: col = lane&15, row = quad*4 + reg  [verified m89/m91]
  #pragma unroll
  for (int mi = 0; mi < 4; ++mi) {
    int rr = r0 + wr + mi * 16 + q * 4;
    #pragma unroll
    for (int ni = 0; ni < 4; ++ni) {
      int cc = j0 + wc + ni * 16 + l15;
      #pragma unroll
      for (int rg = 0; rg < 4; ++rg)
        Y[(size_t)(rr + rg) * CB + cc] = __float2bfloat16(acc[mi][ni][rg]);
    }
  }
}

// ---------------------------------------------------------------- Wm[n][o][KIP] bf16 = sum_d e[n,d] Wp[d,ki,o]  (16 nodes/block)
__global__ __launch_bounds__(256)
void k_wmat(const float* __restrict__ eg, const float* __restrict__ Wp, ushort* __restrict__ Wm) {
  __shared__ float Wl[16 * 8 * 64];  // [d][kr][o] 32 KB
  __shared__ float el[16 * 16];      // [n][d]
  const int t = threadIdx.x;
  const int n0 = blockIdx.x * 16;
  el[t] = eg[n0 * D_ + t];
  const int o = t & 63, ng = t >> 6;
  for (int kic = 0; kic < 17; ++kic) {
    __syncthreads();
    #pragma unroll
    for (int it = 0; it < 8; ++it) {
      int f = it * 256 + t;                       // float4 index 0..2047
      int d = f >> 7, rem = f & 127, kr = rem >> 4, o4 = rem & 15;
      int ki = kic * 8 + kr;
      float4 v;
      if (ki < KI) v = *(const float4*)&Wp[((size_t)d * KI + ki) * 64 + o4 * 4];
      else { v.x = 0.f; v.y = 0.f; v.z = 0.f; v.w = 0.f; }
      *(float4*)&Wl[f * 4] = v;
    }
    __syncthreads();
    float a[4][8];
    #pragma unroll
    for (int j = 0; j < 4; ++j)
      #pragma unroll
      for (int kr = 0; kr < 8; ++kr) a[j][kr] = 0.f;
    for (int d = 0; d < D_; ++d) {
      float w8[8];
      #pragma unroll
      for (int kr = 0; kr < 8; ++kr) w8[kr] = Wl[(d * 8 + kr) * 64 + o];
      #pragma unroll
      for (int j = 0; j < 4; ++j) {
        float ev = el[(ng * 4 + j) * D_ + d];
        #pragma unroll
        for (int kr = 0; kr < 8; ++kr) a[j][kr] = fmaf(ev, w8[kr], a[j][kr]);
      }
    }
    #pragma unroll
    for (int j = 0; j < 4; ++j) {
      const int n = n0 + ng * 4 + j;
      ushort pk[8];
      #pragma unroll
      for (int kr = 0; kr < 8; ++kr) pk[kr] = f2bf(a[j][kr]);
      *(uint4*)&Wm[((size_t)n * 64 + o) * KIP + kic * 8] = *(uint4*)pk;
    }
  }
  // zero tail ki 136..159
  uint4 z = {0, 0, 0, 0};
  #pragma unroll
  for (int j = 0; j < 4; ++j) {
    const int n = n0 + ng * 4 + j;
    ushort* p = &Wm[((size_t)n * 64 + o) * KIP + 136];
    *(uint4*)&p[0] = z; *(uint4*)&p[8] = z; *(uint4*)&p[16] = z;
  }
}

// ---------------------------------------------------------------- per-node einsum via MFMA; B-frags direct from global Wm
template <int MODE>  // 0: sigmoid -> bf16 gate buf ; 1: tanh + GRU combine -> fp32 d_out
__global__ __launch_bounds__(256)
void k_einsum(const float* __restrict__ e, const ushort* __restrict__ Wm, const float* __restrict__ bp,
              const __hip_bfloat16* __restrict__ Y,
              const float* __restrict__ x, const float* __restrict__ state,
              const __hip_bfloat16* __restrict__ zbuf, const __hip_bfloat16* __restrict__ rbuf,
              void* __restrict__ outp) {
  constexpr int LDK = 168;
  constexpr int LDR = 72;
  __shared__ __align__(16) ushort xg[64 * LDK];   // 21504 B : A tile [b][ki]
  __shared__ __align__(16) ushort res[64 * LDR];  //  9216 B : activated result [b][o]
  __shared__ float el[D_];
  __shared__ float bl[64];
  const int n = blockIdx.x, t = threadIdx.x;
  if (t < D_) el[t] = e[n * D_ + t];
  __syncthreads();
  if (t < 64) {
    float s = 0.f;
    #pragma unroll
    for (int d = 0; d < D_; ++d) s += el[d] * bp[d * 64 + t];
    bl[t] = s;
  }
  // ---- build xg[b][ki] = [x(2) | state*(z?) (64) | Y row (66)], bf16, K-pad zeroed
  {
    const int b = t >> 2, j = t & 3;
    const size_t bn = (size_t)b * N_ + n;
    float sv[16];
    const float* sp = state + bn * 64 + j * 16;
    #pragma unroll
    for (int i = 0; i < 16; i += 4) {
      float4 v = *(const float4*)(sp + i);
      sv[i] = v.x; sv[i + 1] = v.y; sv[i + 2] = v.z; sv[i + 3] = v.w;
    }
    if (MODE) {
      const ushort* zp = (const ushort*)zbuf + bn * 64 + j * 16;
      uint4 z0 = *(const uint4*)&zp[0], z1 = *(const uint4*)&zp[8];
      uint zw[8] = {z0.x, z0.y, z0.z, z0.w, z1.x, z1.y, z1.z, z1.w};
      #pragma unroll
      for (int i = 0; i < 8; ++i) {
        sv[2 * i]     *= bf2f((ushort)(zw[i] & 0xffffu));
        sv[2 * i + 1] *= bf2f((ushort)(zw[i] >> 16));
      }
    }
    ushort* xr = &xg[b * LDK + 2 + j * 16];
    #pragma unroll
    for (int i = 0; i < 16; i += 2) {
      uint pk = ((uint)f2bf(sv[i + 1]) << 16) | f2bf(sv[i]);
      *(uint*)&xr[i] = pk;
    }
    const ushort* yp = (const ushort*)Y + (size_t)n * CB + b * C_ + j * 16;
    uint* xy = (uint*)&xg[b * LDK + 66 + j * 16];
    #pragma unroll
    for (int i = 0; i < 8; ++i) xy[i] = *(const uint*)&yp[2 * i];
    if (j == 0) *(uint*)&xg[b * LDK + 130] = *(const uint*)&yp[64];
    if (t < 64) {
      const float* xp = x + ((size_t)t * N_ + n) * DIN;
      uint pk = ((uint)f2bf(xp[1]) << 16) | f2bf(xp[0]);
      *(uint*)&xg[t * LDK] = pk;
    }
    ushort* pg = &xg[b * LDK + 132 + j * 7];
    #pragma unroll
    for (int i = 0; i < 7; ++i) pg[i] = 0;
  }
  __syncthreads();
  // ---- MFMA 64x64, K=KIP; B-frags straight from global (L1/L2-resident 20 KB/block)
  const int l15 = t & 15, q = (t >> 4) & 3, w = t >> 6;
  const int wm = (w >> 1) * 32, wn = (w & 1) * 32;
  const ushort* Wn = Wm + (size_t)n * (64 * KIP);
  f4 acc[2][2];
  acc[0][0] = acc[0][1] = acc[1][0] = acc[1][1] = (f4)0.0f;
  #pragma unroll
  for (int kk = 0; kk < KIP; kk += 32) {
    s8 af[2], bfr[2];
    #pragma unroll
    for (int mi = 0; mi < 2; ++mi) af[mi] = *(const s8*)&xg[(wm + mi * 16 + l15) * LDK + kk + q * 8];
    #pragma unroll
    for (int ni = 0; ni < 2; ++ni) bfr[ni] = *(const s8*)(Wn + (size_t)(wn + ni * 16 + l15) * KIP + kk + q * 8);
    #pragma unroll
    for (int mi = 0; mi < 2; ++mi)
      #pragma unroll
      for (int ni = 0; ni < 2; ++ni)
        acc[mi][ni] = __builtin_amdgcn_mfma_f32_16x16x32_bf16(af[mi], bfr[ni], acc[mi][ni], 0, 0, 0);
  }
  {
    float bl0 = bl[wn + l15], bl1 = bl[wn + 16 + l15];
    #pragma unroll
    for (int mi = 0; mi < 2; ++mi)
      #pragma unroll
      for (int ni = 0; ni < 2; ++ni) {
        float bb = ni ? bl1 : bl0;
        #pragma unroll
        for (int rg = 0; rg < 4; ++rg) {
          float v = acc[mi][ni][rg] + bb;
          float a;
          if (MODE == 0) a = 1.0f / (1.0f + __expf(-v));
          else           a = 1.0f - 2.0f / (__expf(2.0f * v) + 1.0f);
          res[(wm + mi * 16 + q * 4 + rg) * LDR + (wn + ni * 16 + l15)] = f2bf(a);
        }
      }
  }
  __syncthreads();
  {
    const int b = t >> 2, j = t & 3;
    const size_t gb = ((size_t)b * N_ + n) * 64 + j * 16;
    const ushort* rr = &res[b * LDR + j * 16];
    if (MODE == 0) {
      uint4 v0 = *(const uint4*)&rr[0];
      uint4 v1 = *(const uint4*)&rr[8];
      *(uint4*)((ushort*)outp + gb) = v0;
      *(uint4*)((ushort*)outp + gb + 8) = v1;
    } else {
      float* ob = (float*)outp;
      const float* stp = state + gb;
      const ushort* rp = (const ushort*)rbuf + gb;
      uint4 r0 = *(const uint4*)&rp[0], r1 = *(const uint4*)&rp[8];
      uint rw[8] = {r0.x, r0.y, r0.z, r0.w, r1.x, r1.y, r1.z, r1.w};
      #pragma unroll
      for (int i = 0; i < 16; i += 4) {
        float4 st = *(const float4*)(stp + i);
        float4 ov;
        float rv0 = bf2f((ushort)(rw[i / 2] & 0xffffu));
        float rv1 = bf2f((ushort)(rw[i / 2] >> 16));
        float rv2 = bf2f((ushort)(rw[i / 2 + 1] & 0xffffu));
        float rv3 = bf2f((ushort)(rw[i / 2 + 1] >> 16));
        ov.x = rv0 * st.x + (1.0f - rv0) * bf2f(rr[i]);
        ov.y = rv1 * st.y + (1.0f - rv1) * bf2f(rr[i + 1]);
        ov.z = rv2 * st.z + (1.0f - rv2) * bf2f(rr[i + 2]);
        ov.w = rv3 * st.w + (1.0f - rv3) * bf2f(rr[i + 3]);
        *(float4*)(ob + gb + i) = ov;
      }
    }
  }
}

// ----------------------------------------------------------------
extern "C" void kernel_launch(void* const* d_in, const int* in_sizes, int n_in,
                              void* d_out, int out_size, void* d_ws, size_t ws_size,
                              hipStream_t stream) {
  const float* x     = (const float*)d_in[0];
  const float* state = (const float*)d_in[1];
  const float* node  = (const float*)d_in[2];
  const float* timee = (const float*)d_in[3];
  const float* W_z = (const float*)d_in[4];
  const float* b_z = (const float*)d_in[5];
  const float* g_z = (const float*)d_in[6];
  const float* be_z = (const float*)d_in[7];
  const float* W_r = (const float*)d_in[8];
  const float* b_r = (const float*)d_in[9];
  const float* g_r = (const float*)d_in[10];
  const float* be_r = (const float*)d_in[11];
  const float* W_u = (const float*)d_in[12];
  const float* b_u = (const float*)d_in[13];
  const float* g_u = (const float*)d_in[14];
  const float* be_u = (const float*)d_in[15];

  constexpr size_t NN = (size_t)N_ * N_;
  constexpr size_t ND = (size_t)N_ * D_;
  // Workspace layout (bytes), total ~135.7 MB:
  char* ws = (char*)d_ws;
  float*           e  = (float*)(ws);                        // 393,216
  __hip_bfloat16*  A  = (__hip_bfloat16*)(ws + 393216);      // 25,165,824
  __hip_bfloat16*  XT = (__hip_bfloat16*)(ws + 25559040);    // 17,301,504
  __hip_bfloat16*  Y  = (__hip_bfloat16*)(ws + 42860544);    // 17,301,504
  __hip_bfloat16*  zb = (__hip_bfloat16*)(ws + 60162048);    // 16,777,216
  __hip_bfloat16*  rb = (__hip_bfloat16*)(ws + 76939264);    // 16,777,216
  // S (16.8 MB fp32) aliases Wm (41.9 MB bf16): S consumed before first k_wmat.
  float*           S  = (float*)(ws + 93716480);
  ushort*          Wm = (ushort*)(ws + 93716480);            // 2048*64*160*2 = 41,943,040

  float* out = (float*)d_out;

  k_e<<<8, 256, 0, stream>>>(node, timee, g_z, be_z, g_r, be_r, g_u, be_u, e);
  for (int g = 0; g < 3; ++g) {
    k_S<<<dim3(16, 16), 256, 0, stream>>>(e + g * ND, S);
    k_rowsm<<<N_, 256, 0, stream>>>(S, A + g * NN);
  }
  k_buildX<0><<<dim3(32, 64), 256, 0, stream>>>(x, state, nullptr, XT);

  dim3 ggrid(CB / 128, N_ / 128);  // 33 x 16

  // gate z
  k_wmat<<<128, 256, 0, stream>>>(e + 0 * ND, W_z, Wm);
  k_gemm<<<ggrid, 256, 0, stream>>>(A + 0 * NN, XT, Y);
  k_einsum<0><<<N_, 256, 0, stream>>>(e + 0 * ND, Wm, b_z, Y, x, state, nullptr, nullptr, (void*)zb);
  // gate r
  k_wmat<<<128, 256, 0, stream>>>(e + 1 * ND, W_r, Wm);
  k_gemm<<<ggrid, 256, 0, stream>>>(A + 1 * NN, XT, Y);
  k_einsum<0><<<N_, 256, 0, stream>>>(e + 1 * ND, Wm, b_r, Y, x, state, nullptr, nullptr, (void*)rb);
  // gate u: cand = [x, z*state]
  k_buildX<1><<<dim3(32, 64), 256, 0, stream>>>(x, state, zb, XT);
  k_wmat<<<128, 256, 0, stream>>>(e + 2 * ND, W_u, Wm);
  k_gemm<<<ggrid, 256, 0, stream>>>(A + 2 * NN, XT, Y);
  k_einsum<1><<<N_, 256, 0, stream>>>(e + 2 * ND, Wm, b_u, Y, x, state, zb, rb, (void*)out);
}

// Round 5
// 517.290 us; speedup vs baseline: 1.8602x; 1.2040x over previous
//
#include <hip/hip_runtime.h>
#include <hip/hip_bf16.h>
#include <math.h>

// GRUCell with adaptive-graph GCN on MI355X (gfx950).
// B=64, N=2048, Din=2, H=64, D=16, C=66, O=64.
// R5: k_wmat rewritten — 1024 blocks (8 nodes x ki-quarter), e-rows in VGPRs,
//     LDS-staged 32-ki slabs flushed as full-line dwordx4 (kills 2x write amplification
//     + 5% occupancy latency-bound behavior of R4's 128-block version).

typedef __attribute__((ext_vector_type(4))) float f4;
typedef __attribute__((ext_vector_type(8))) short s8;  // 8 bf16 in 4 VGPRs (MFMA A/B frag)

#define B_   64
#define N_   2048
#define DIN  2
#define H_   64
#define D_   16
#define C_   66    // DIN + H
#define KI   132   // 2*C
#define KIP  160   // KI padded for K-loop (multiple of 32)
#define CB   4224  // B_*C_

#define GLD16(gp, lp) __builtin_amdgcn_global_load_lds((const __attribute__((address_space(1))) void*)(gp), (__attribute__((address_space(3))) void*)(lp), 16, 0, 0)

static __device__ __forceinline__ ushort f2bf(float v) {
  __hip_bfloat16 h = __float2bfloat16(v);
  return *(ushort*)&h;
}
static __device__ __forceinline__ float bf2f(ushort u) {
  __hip_bfloat16 h = *(__hip_bfloat16*)&u;
  return __bfloat162float(h);
}
static __device__ __forceinline__ uint packbf(float a, float b) {
  return ((uint)f2bf(b) << 16) | f2bf(a);
}

// ---------------------------------------------------------------- e = LN(node+time)*gamma+beta
__global__ void k_e(const float* __restrict__ node, const float* __restrict__ timee,
                    const float* __restrict__ g0, const float* __restrict__ b0,
                    const float* __restrict__ g1, const float* __restrict__ b1,
                    const float* __restrict__ g2, const float* __restrict__ b2,
                    float* __restrict__ e) {
  int n = blockIdx.x * blockDim.x + threadIdx.x;
  if (n >= N_) return;
  float v[D_]; float m = 0.f;
  #pragma unroll
  for (int d = 0; d < D_; ++d) { v[d] = node[n * D_ + d] + timee[d]; m += v[d]; }
  m *= (1.0f / D_);
  float var = 0.f;
  #pragma unroll
  for (int d = 0; d < D_; ++d) { float t = v[d] - m; var += t * t; }
  var *= (1.0f / D_);
  float r = rsqrtf(var + 1e-12f);
  #pragma unroll
  for (int d = 0; d < D_; ++d) {
    float y = (v[d] - m) * r;
    e[0 * N_ * D_ + n * D_ + d] = y * g0[d] + b0[d];
    e[1 * N_ * D_ + n * D_ + d] = y * g1[d] + b1[d];
    e[2 * N_ * D_ + n * D_ + d] = y * g2[d] + b2[d];
  }
}

// ---------------------------------------------------------------- S = e_g @ e_g^T (fp32 out), MFMA K=16 padded to 32
__global__ __launch_bounds__(256)
void k_S(const float* __restrict__ eg, float* __restrict__ S) {
  __shared__ __align__(16) ushort At[128 * 32];
  __shared__ __align__(16) ushort Bt[128 * 32];
  const int t = threadIdx.x;
  const int c0 = blockIdx.x * 128, r0 = blockIdx.y * 128;
  const int row = t >> 1, half = t & 1;
  {
    const float* p = eg + (size_t)(r0 + row) * D_ + half * 8;
    float4 a = *(const float4*)p, b = *(const float4*)(p + 4);
    ushort pk[8] = {f2bf(a.x), f2bf(a.y), f2bf(a.z), f2bf(a.w), f2bf(b.x), f2bf(b.y), f2bf(b.z), f2bf(b.w)};
    *(uint4*)&At[row * 32 + half * 8] = *(uint4*)pk;
    uint4 z = {0, 0, 0, 0};
    *(uint4*)&At[row * 32 + 16 + half * 8] = z;
    const float* q2 = eg + (size_t)(c0 + row) * D_ + half * 8;
    float4 c = *(const float4*)q2, d = *(const float4*)(q2 + 4);
    ushort pk2[8] = {f2bf(c.x), f2bf(c.y), f2bf(c.z), f2bf(c.w), f2bf(d.x), f2bf(d.y), f2bf(d.z), f2bf(d.w)};
    *(uint4*)&Bt[row * 32 + half * 8] = *(uint4*)pk2;
    *(uint4*)&Bt[row * 32 + 16 + half * 8] = z;
  }
  __syncthreads();
  const int l15 = t & 15, q = (t >> 4) & 3, w = t >> 6;
  const int wr = (w >> 1) * 64, wc = (w & 1) * 64;
  s8 af[4], bf[4];
  #pragma unroll
  for (int mi = 0; mi < 4; ++mi) af[mi] = *(const s8*)&At[(wr + mi * 16 + l15) * 32 + q * 8];
  #pragma unroll
  for (int ni = 0; ni < 4; ++ni) bf[ni] = *(const s8*)&Bt[(wc + ni * 16 + l15) * 32 + q * 8];
  f4 acc[4][4];
  #pragma unroll
  for (int i = 0; i < 4; ++i)
    #pragma unroll
    for (int j = 0; j < 4; ++j) acc[i][j] = (f4)0.0f;
  #pragma unroll
  for (int mi = 0; mi < 4; ++mi)
    #pragma unroll
    for (int ni = 0; ni < 4; ++ni)
      acc[mi][ni] = __builtin_amdgcn_mfma_f32_16x16x32_bf16(af[mi], bf[ni], acc[mi][ni], 0, 0, 0);
  #pragma unroll
  for (int mi = 0; mi < 4; ++mi) {
    int rr = r0 + wr + mi * 16 + q * 4;
    #pragma unroll
    for (int ni = 0; ni < 4; ++ni) {
      int cc = c0 + wc + ni * 16 + l15;
      #pragma unroll
      for (int rg = 0; rg < 4; ++rg)
        S[(size_t)(rr + rg) * N_ + cc] = acc[mi][ni][rg];
    }
  }
}

// ---------------------------------------------------------------- row softmax: A = softmax(S, axis=1), bf16
__global__ __launch_bounds__(256)
void k_rowsm(const float* __restrict__ S, __hip_bfloat16* __restrict__ A) {
  __shared__ float red[256];
  const int r = blockIdx.x, t = threadIdx.x;
  const float* Sr = S + (size_t)r * N_;
  float4 v0 = ((const float4*)Sr)[t];
  float4 v1 = ((const float4*)Sr)[t + 256];
  float mx = fmaxf(fmaxf(fmaxf(v0.x, v0.y), fmaxf(v0.z, v0.w)),
                   fmaxf(fmaxf(v1.x, v1.y), fmaxf(v1.z, v1.w)));
  red[t] = mx; __syncthreads();
  for (int st = 128; st > 0; st >>= 1) { if (t < st) red[t] = fmaxf(red[t], red[t + st]); __syncthreads(); }
  const float gmax = red[0]; __syncthreads();
  float e0 = __expf(v0.x - gmax), e1 = __expf(v0.y - gmax), e2 = __expf(v0.z - gmax), e3 = __expf(v0.w - gmax);
  float e4 = __expf(v1.x - gmax), e5 = __expf(v1.y - gmax), e6 = __expf(v1.z - gmax), e7 = __expf(v1.w - gmax);
  red[t] = e0 + e1 + e2 + e3 + e4 + e5 + e6 + e7; __syncthreads();
  for (int st = 128; st > 0; st >>= 1) { if (t < st) red[t] += red[t + st]; __syncthreads(); }
  const float inv = 1.0f / red[0];
  ushort* Ar = (ushort*)A + (size_t)r * N_;
  ushort p0[4] = {f2bf(e0 * inv), f2bf(e1 * inv), f2bf(e2 * inv), f2bf(e3 * inv)};
  ushort p1[4] = {f2bf(e4 * inv), f2bf(e5 * inv), f2bf(e6 * inv), f2bf(e7 * inv)};
  *(uint2*)&Ar[t * 4] = *(uint2*)p0;
  *(uint2*)&Ar[1024 + t * 4] = *(uint2*)p1;
}

// ---------------------------------------------------------------- X^T[j=b*C+c][m] bf16 via LDS transpose
template <int MODE>  // 0: xs=[x,state]   1: cand=[x, z*state]
__global__ __launch_bounds__(256)
void k_buildX(const float* __restrict__ x, const float* __restrict__ state,
              const __hip_bfloat16* __restrict__ zbuf, __hip_bfloat16* __restrict__ XT) {
  constexpr int LDM = 72;  // row stride (shorts), 144 B: 16B-aligned rows
  __shared__ __align__(16) ushort T[C_ * LDM];
  const int t = threadIdx.x;
  const int m0 = blockIdx.x * 64, b = blockIdx.y;
  const int m = t >> 2, hq = t & 3;
  {
    const float* sp = state + ((size_t)b * N_ + m0 + m) * H_ + hq * 16;
    float sv[16];
    #pragma unroll
    for (int i = 0; i < 16; i += 4) {
      float4 v = *(const float4*)(sp + i);
      sv[i] = v.x; sv[i + 1] = v.y; sv[i + 2] = v.z; sv[i + 3] = v.w;
    }
    if (MODE) {
      const ushort* zp = (const ushort*)zbuf + ((size_t)b * N_ + m0 + m) * H_ + hq * 16;
      uint4 z0 = *(const uint4*)&zp[0], z1 = *(const uint4*)&zp[8];
      uint zw[8] = {z0.x, z0.y, z0.z, z0.w, z1.x, z1.y, z1.z, z1.w};
      #pragma unroll
      for (int i = 0; i < 8; ++i) {
        sv[2 * i]     *= bf2f((ushort)(zw[i] & 0xffffu));
        sv[2 * i + 1] *= bf2f((ushort)(zw[i] >> 16));
      }
    }
    #pragma unroll
    for (int i = 0; i < 16; ++i) T[(DIN + hq * 16 + i) * LDM + m] = f2bf(sv[i]);
    if (t < 64) {
      const float2 xv = *(const float2*)&x[((size_t)b * N_ + m0 + t) * DIN];
      T[0 * LDM + t] = f2bf(xv.x);
      T[1 * LDM + t] = f2bf(xv.y);
    }
  }
  __syncthreads();
  {
    int r = t >> 2, ch = t & 3;
    ushort* dst = (ushort*)XT + (size_t)(b * C_ + r) * N_ + m0 + ch * 16;
    *(uint4*)&dst[0] = *(uint4*)&T[r * LDM + ch * 16];
    *(uint4*)&dst[8] = *(uint4*)&T[r * LDM + ch * 16 + 8];
    if (t < 8) {
      r = 64 + (t >> 2);
      ushort* dst2 = (ushort*)XT + (size_t)(b * C_ + r) * N_ + m0 + ch * 16;
      *(uint4*)&dst2[0] = *(uint4*)&T[r * LDM + ch * 16];
      *(uint4*)&dst2[8] = *(uint4*)&T[r * LDM + ch * 16 + 8];
    }
  }
}

// ---------------------------------------------------------------- Y[r,j] = sum_m A[r,m] XT[j,m]  (m97: global_load_lds staging)
__global__ __launch_bounds__(256)
void k_gemm(const __hip_bfloat16* __restrict__ Ag, const __hip_bfloat16* __restrict__ XT,
            __hip_bfloat16* __restrict__ Y) {
  __shared__ __align__(16) ushort At[128 * 32];
  __shared__ __align__(16) ushort Xt[128 * 32];
  const int t = threadIdx.x;
  const int j0 = blockIdx.x * 128, r0 = blockIdx.y * 128;
  const int lane = t & 63, w = t >> 6;
  const int rowa = w * 32 + (lane >> 2), kc = (lane & 3) * 8;
  const ushort* gA = (const ushort*)Ag + (size_t)(r0 + rowa) * N_ + kc;
  const ushort* gX = (const ushort*)XT + (size_t)(j0 + rowa) * N_ + kc;
  ushort* lA0 = &At[(w * 32) * 32];       // wave-uniform LDS bases; HW scatters lane*16B
  ushort* lA1 = &At[(w * 32 + 16) * 32];
  ushort* lX0 = &Xt[(w * 32) * 32];
  ushort* lX1 = &Xt[(w * 32 + 16) * 32];
  const int l15 = t & 15, q = (t >> 4) & 3;
  const int wr = (w >> 1) * 64, wc = (w & 1) * 64;
  f4 acc[4][4];
  #pragma unroll
  for (int i = 0; i < 4; ++i)
    #pragma unroll
    for (int jj = 0; jj < 4; ++jj) acc[i][jj] = (f4)0.0f;
  for (int k0 = 0; k0 < N_; k0 += 32) {
    __syncthreads();
    GLD16(gA + k0, lA0);
    GLD16(gA + 16 * N_ + k0, lA1);
    GLD16(gX + k0, lX0);
    GLD16(gX + 16 * N_ + k0, lX1);
    __syncthreads();   // compiler drains vmcnt(0) before s_barrier -> LDS data visible
    s8 af[4], bf[4];
    #pragma unroll
    for (int mi = 0; mi < 4; ++mi) af[mi] = *(const s8*)&At[(wr + mi * 16 + l15) * 32 + q * 8];
    #pragma unroll
    for (int ni = 0; ni < 4; ++ni) bf[ni] = *(const s8*)&Xt[(wc + ni * 16 + l15) * 32 + q * 8];
    #pragma unroll
    for (int mi = 0; mi < 4; ++mi)
      #pragma unroll
      for (int ni = 0; ni < 4; ++ni)
        acc[mi][ni] = __builtin_amdgcn_mfma_f32_16x16x32_bf16(af[mi], bf[ni], acc[mi][ni], 0, 0, 0);
  }
  // C/D: col = lane&15, row = quad*4 + reg  [verified m89/m91]
  #pragma unroll
  for (int mi = 0; mi < 4; ++mi) {
    int rr = r0 + wr + mi * 16 + q * 4;
    #pragma unroll
    for (int ni = 0; ni < 4; ++ni) {
      int cc = j0 + wc + ni * 16 + l15;
      #pragma unroll
      for (int rg = 0; rg < 4; ++rg)
        Y[(size_t)(rr + rg) * CB + cc] = __float2bfloat16(acc[mi][ni][rg]);
    }
  }
}

// ---------------------------------------------------------------- Wm[n][o][KIP] bf16 = sum_d e[n,d] Wp[d,ki,o]
// R5: grid (256, 4): 8 nodes x ki-quarter per block. e-rows in VGPRs.
// Results staged in LDS Tr per 32-ki slab, flushed as full-64B-line dwordx4.
__global__ __launch_bounds__(256)
void k_wmat(const float* __restrict__ eg, const float* __restrict__ Wp, ushort* __restrict__ Wm) {
  constexpr int TRS = 36;  // Tr row stride (shorts): 18 words, gcd(18,32)=2 -> <=4-way banked; 8-B aligned
  __shared__ float Wl[16 * 8 * 64];     // [d][kr][o]  32 KB (one kic chunk of 8 ki)
  __shared__ ushort Tr[8 * 64 * TRS];   // [n][o][36]  36.9 KB (one 32-ki slab)
  const int t = threadIdx.x;
  const int n0 = blockIdx.x * 8;
  const int y = blockIdx.y;             // ki-quarter; y==3 covers kic 12..19 (incl. zero tail)
  const int o = t & 63, w = t >> 6;
  const int ng = w & 1, krh = (w >> 1) * 4;   // nodes ng*4..+3 ; kr krh..krh+3
  float er[4][16];
  #pragma unroll
  for (int j = 0; j < 4; ++j) {
    const float* ep = eg + (size_t)(n0 + ng * 4 + j) * D_;
    #pragma unroll
    for (int d = 0; d < D_; d += 4) {
      float4 v = *(const float4*)(ep + d);
      er[j][d] = v.x; er[j][d + 1] = v.y; er[j][d + 2] = v.z; er[j][d + 3] = v.w;
    }
  }
  const int ngroups = (y == 3) ? 2 : 1;
  for (int g = 0; g < ngroups; ++g) {
    const int kic0 = y * 4 + g * 4;
    for (int kk = 0; kk < 4; ++kk) {
      const int kic = kic0 + kk;
      __syncthreads();                  // Wl reusable; Tr flush (prev group) complete
      #pragma unroll
      for (int it = 0; it < 8; ++it) {
        int f = it * 256 + t;           // float4 index over [16d][8kr][16 o4]
        int d = f >> 7, rem = f & 127, kr = rem >> 4, o4 = rem & 15;
        int ki = kic * 8 + kr;
        float4 v;
        if (ki < KI) v = *(const float4*)&Wp[((size_t)d * KI + ki) * 64 + o4 * 4];
        else { v.x = 0.f; v.y = 0.f; v.z = 0.f; v.w = 0.f; }
        *(float4*)&Wl[f * 4] = v;
      }
      __syncthreads();
      float a[4][4];
      #pragma unroll
      for (int j = 0; j < 4; ++j)
        #pragma unroll
        for (int k = 0; k < 4; ++k) a[j][k] = 0.f;
      for (int d = 0; d < D_; ++d) {
        float w4[4];
        #pragma unroll
        for (int k = 0; k < 4; ++k) w4[k] = Wl[(d * 8 + krh + k) * 64 + o];
        #pragma unroll
        for (int j = 0; j < 4; ++j)
          #pragma unroll
          for (int k = 0; k < 4; ++k) a[j][k] = fmaf(er[j][d], w4[k], a[j][k]);
      }
      #pragma unroll
      for (int j = 0; j < 4; ++j) {
        ushort* tr = &Tr[((ng * 4 + j) * 64 + o) * TRS + kk * 8 + krh];
        *(uint*)&tr[0] = packbf(a[j][0], a[j][1]);
        *(uint*)&tr[2] = packbf(a[j][2], a[j][3]);
      }
    }
    __syncthreads();
    // flush the 32-ki slab, full 64-B lines: lanes = (q fast, o next)
    const int k0 = kic0 * 8;
    #pragma unroll
    for (int p = 0; p < 8; ++p) {
      int u = p * 256 + t;
      int nl = u >> 8, oo = (u >> 2) & 63, q = u & 3;
      const ushort* tr = &Tr[(nl * 64 + oo) * TRS + q * 8];
      uint2 lo = *(const uint2*)&tr[0];
      uint2 hi = *(const uint2*)&tr[4];
      uint4 vv; vv.x = lo.x; vv.y = lo.y; vv.z = hi.x; vv.w = hi.y;
      *(uint4*)&Wm[((size_t)(n0 + nl) * 64 + oo) * KIP + k0 + q * 8] = vv;
    }
  }
}

// ---------------------------------------------------------------- per-node einsum via MFMA; B-frags direct from global Wm
template <int MODE>  // 0: sigmoid -> bf16 gate buf ; 1: tanh + GRU combine -> fp32 d_out
__global__ __launch_bounds__(256)
void k_einsum(const float* __restrict__ e, const ushort* __restrict__ Wm, const float* __restrict__ bp,
              const __hip_bfloat16* __restrict__ Y,
              const float* __restrict__ x, const float* __restrict__ state,
              const __hip_bfloat16* __restrict__ zbuf, const __hip_bfloat16* __restrict__ rbuf,
              void* __restrict__ outp) {
  constexpr int LDK = 168;
  constexpr int LDR = 72;
  __shared__ __align__(16) ushort xg[64 * LDK];   // 21504 B : A tile [b][ki]
  __shared__ __align__(16) ushort res[64 * LDR];  //  9216 B : activated result [b][o]
  __shared__ float el[D_];
  __shared__ float bl[64];
  const int n = blockIdx.x, t = threadIdx.x;
  if (t < D_) el[t] = e[n * D_ + t];
  __syncthreads();
  if (t < 64) {
    float s = 0.f;
    #pragma unroll
    for (int d = 0; d < D_; ++d) s += el[d] * bp[d * 64 + t];
    bl[t] = s;
  }
  // ---- build xg[b][ki] = [x(2) | state*(z?) (64) | Y row (66)], bf16, K-pad zeroed
  {
    const int b = t >> 2, j = t & 3;
    const size_t bn = (size_t)b * N_ + n;
    float sv[16];
    const float* sp = state + bn * 64 + j * 16;
    #pragma unroll
    for (int i = 0; i < 16; i += 4) {
      float4 v = *(const float4*)(sp + i);
      sv[i] = v.x; sv[i + 1] = v.y; sv[i + 2] = v.z; sv[i + 3] = v.w;
    }
    if (MODE) {
      const ushort* zp = (const ushort*)zbuf + bn * 64 + j * 16;
      uint4 z0 = *(const uint4*)&zp[0], z1 = *(const uint4*)&zp[8];
      uint zw[8] = {z0.x, z0.y, z0.z, z0.w, z1.x, z1.y, z1.z, z1.w};
      #pragma unroll
      for (int i = 0; i < 8; ++i) {
        sv[2 * i]     *= bf2f((ushort)(zw[i] & 0xffffu));
        sv[2 * i + 1] *= bf2f((ushort)(zw[i] >> 16));
      }
    }
    ushort* xr = &xg[b * LDK + 2 + j * 16];
    #pragma unroll
    for (int i = 0; i < 16; i += 2) {
      uint pk = packbf(sv[i], sv[i + 1]);
      *(uint*)&xr[i] = pk;
    }
    const ushort* yp = (const ushort*)Y + (size_t)n * CB + b * C_ + j * 16;
    uint* xy = (uint*)&xg[b * LDK + 66 + j * 16];
    #pragma unroll
    for (int i = 0; i < 8; ++i) xy[i] = *(const uint*)&yp[2 * i];
    if (j == 0) *(uint*)&xg[b * LDK + 130] = *(const uint*)&yp[64];
    if (t < 64) {
      const float* xp = x + ((size_t)t * N_ + n) * DIN;
      uint pk = packbf(xp[0], xp[1]);
      *(uint*)&xg[t * LDK] = pk;
    }
    ushort* pg = &xg[b * LDK + 132 + j * 7];
    #pragma unroll
    for (int i = 0; i < 7; ++i) pg[i] = 0;
  }
  __syncthreads();
  // ---- MFMA 64x64, K=KIP; B-frags straight from global (L1/L2-resident 20 KB/block)
  const int l15 = t & 15, q = (t >> 4) & 3, w = t >> 6;
  const int wm = (w >> 1) * 32, wn = (w & 1) * 32;
  const ushort* Wn = Wm + (size_t)n * (64 * KIP);
  f4 acc[2][2];
  acc[0][0] = acc[0][1] = acc[1][0] = acc[1][1] = (f4)0.0f;
  #pragma unroll
  for (int kk = 0; kk < KIP; kk += 32) {
    s8 af[2], bfr[2];
    #pragma unroll
    for (int mi = 0; mi < 2; ++mi) af[mi] = *(const s8*)&xg[(wm + mi * 16 + l15) * LDK + kk + q * 8];
    #pragma unroll
    for (int ni = 0; ni < 2; ++ni) bfr[ni] = *(const s8*)(Wn + (size_t)(wn + ni * 16 + l15) * KIP + kk + q * 8);
    #pragma unroll
    for (int mi = 0; mi < 2; ++mi)
      #pragma unroll
      for (int ni = 0; ni < 2; ++ni)
        acc[mi][ni] = __builtin_amdgcn_mfma_f32_16x16x32_bf16(af[mi], bfr[ni], acc[mi][ni], 0, 0, 0);
  }
  {
    float bl0 = bl[wn + l15], bl1 = bl[wn + 16 + l15];
    #pragma unroll
    for (int mi = 0; mi < 2; ++mi)
      #pragma unroll
      for (int ni = 0; ni < 2; ++ni) {
        float bb = ni ? bl1 : bl0;
        #pragma unroll
        for (int rg = 0; rg < 4; ++rg) {
          float v = acc[mi][ni][rg] + bb;
          float a;
          if (MODE == 0) a = 1.0f / (1.0f + __expf(-v));
          else           a = 1.0f - 2.0f / (__expf(2.0f * v) + 1.0f);
          res[(wm + mi * 16 + q * 4 + rg) * LDR + (wn + ni * 16 + l15)] = f2bf(a);
        }
      }
  }
  __syncthreads();
  {
    const int b = t >> 2, j = t & 3;
    const size_t gb = ((size_t)b * N_ + n) * 64 + j * 16;
    const ushort* rr = &res[b * LDR + j * 16];
    if (MODE == 0) {
      uint4 v0 = *(const uint4*)&rr[0];
      uint4 v1 = *(const uint4*)&rr[8];
      *(uint4*)((ushort*)outp + gb) = v0;
      *(uint4*)((ushort*)outp + gb + 8) = v1;
    } else {
      float* ob = (float*)outp;
      const float* stp = state + gb;
      const ushort* rp = (const ushort*)rbuf + gb;
      uint4 r0 = *(const uint4*)&rp[0], r1 = *(const uint4*)&rp[8];
      uint rw[8] = {r0.x, r0.y, r0.z, r0.w, r1.x, r1.y, r1.z, r1.w};
      #pragma unroll
      for (int i = 0; i < 16; i += 4) {
        float4 st = *(const float4*)(stp + i);
        float4 ov;
        float rv0 = bf2f((ushort)(rw[i / 2] & 0xffffu));
        float rv1 = bf2f((ushort)(rw[i / 2] >> 16));
        float rv2 = bf2f((ushort)(rw[i / 2 + 1] & 0xffffu));
        float rv3 = bf2f((ushort)(rw[i / 2 + 1] >> 16));
        ov.x = rv0 * st.x + (1.0f - rv0) * bf2f(rr[i]);
        ov.y = rv1 * st.y + (1.0f - rv1) * bf2f(rr[i + 1]);
        ov.z = rv2 * st.z + (1.0f - rv2) * bf2f(rr[i + 2]);
        ov.w = rv3 * st.w + (1.0f - rv3) * bf2f(rr[i + 3]);
        *(float4*)(ob + gb + i) = ov;
      }
    }
  }
}

// ----------------------------------------------------------------
extern "C" void kernel_launch(void* const* d_in, const int* in_sizes, int n_in,
                              void* d_out, int out_size, void* d_ws, size_t ws_size,
                              hipStream_t stream) {
  const float* x     = (const float*)d_in[0];
  const float* state = (const float*)d_in[1];
  const float* node  = (const float*)d_in[2];
  const float* timee = (const float*)d_in[3];
  const float* W_z = (const float*)d_in[4];
  const float* b_z = (const float*)d_in[5];
  const float* g_z = (const float*)d_in[6];
  const float* be_z = (const float*)d_in[7];
  const float* W_r = (const float*)d_in[8];
  const float* b_r = (const float*)d_in[9];
  const float* g_r = (const float*)d_in[10];
  const float* be_r = (const float*)d_in[11];
  const float* W_u = (const float*)d_in[12];
  const float* b_u = (const float*)d_in[13];
  const float* g_u = (const float*)d_in[14];
  const float* be_u = (const float*)d_in[15];

  constexpr size_t NN = (size_t)N_ * N_;
  constexpr size_t ND = (size_t)N_ * D_;
  // Workspace layout (bytes), total ~135.7 MB:
  char* ws = (char*)d_ws;
  float*           e  = (float*)(ws);                        // 393,216
  __hip_bfloat16*  A  = (__hip_bfloat16*)(ws + 393216);      // 25,165,824
  __hip_bfloat16*  XT = (__hip_bfloat16*)(ws + 25559040);    // 17,301,504
  __hip_bfloat16*  Y  = (__hip_bfloat16*)(ws + 42860544);    // 17,301,504
  __hip_bfloat16*  zb = (__hip_bfloat16*)(ws + 60162048);    // 16,777,216
  __hip_bfloat16*  rb = (__hip_bfloat16*)(ws + 76939264);    // 16,777,216
  // S (16.8 MB fp32) aliases Wm (41.9 MB bf16): S consumed before first k_wmat.
  float*           S  = (float*)(ws + 93716480);
  ushort*          Wm = (ushort*)(ws + 93716480);            // 2048*64*160*2 = 41,943,040

  float* out = (float*)d_out;

  k_e<<<8, 256, 0, stream>>>(node, timee, g_z, be_z, g_r, be_r, g_u, be_u, e);
  for (int g = 0; g < 3; ++g) {
    k_S<<<dim3(16, 16), 256, 0, stream>>>(e + g * ND, S);
    k_rowsm<<<N_, 256, 0, stream>>>(S, A + g * NN);
  }
  k_buildX<0><<<dim3(32, 64), 256, 0, stream>>>(x, state, nullptr, XT);

  dim3 ggrid(CB / 128, N_ / 128);  // 33 x 16
  dim3 wgrid(N_ / 8, 4);           // 256 x 4 = 1024 blocks

  // gate z
  k_wmat<<<wgrid, 256, 0, stream>>>(e + 0 * ND, W_z, Wm);
  k_gemm<<<ggrid, 256, 0, stream>>>(A + 0 * NN, XT, Y);
  k_einsum<0><<<N_, 256, 0, stream>>>(e + 0 * ND, Wm, b_z, Y, x, state, nullptr, nullptr, (void*)zb);
  // gate r
  k_wmat<<<wgrid, 256, 0, stream>>>(e + 1 * ND, W_r, Wm);
  k_gemm<<<ggrid, 256, 0, stream>>>(A + 1 * NN, XT, Y);
  k_einsum<0><<<N_, 256, 0, stream>>>(e + 1 * ND, Wm, b_r, Y, x, state, nullptr, nullptr, (void*)rb);
  // gate u: cand = [x, z*state]
  k_buildX<1><<<dim3(32, 64), 256, 0, stream>>>(x, state, zb, XT);
  k_wmat<<<wgrid, 256, 0, stream>>>(e + 2 * ND, W_u, Wm);
  k_gemm<<<ggrid, 256, 0, stream>>>(A + 2 * NN, XT, Y);
  k_einsum<1><<<N_, 256, 0, stream>>>(e + 2 * ND, Wm, b_u, Y, x, state, zb, rb, (void*)out);
}

// Round 8
// 494.288 us; speedup vs baseline: 1.9467x; 1.0465x over previous
//
#include <hip/hip_runtime.h>
#include <hip/hip_bf16.h>
#include <math.h>

// GRUCell with adaptive-graph GCN on MI355X (gfx950).
// B=64, N=2048, Din=2, H=64, D=16, C=66, O=64.
// R8: R7 + THE fix — k_gemm epilogue stored __hip_bfloat16 into ushort* (implicit
//     operator float() -> integer truncation of the VALUE, silently zeroing Y).
//     Now stores f2bf() bits. Fused z+r GEMM and fused S/rowsm retained; dbuf still out.

typedef __attribute__((ext_vector_type(4))) float f4;
typedef __attribute__((ext_vector_type(8))) short s8;  // 8 bf16 in 4 VGPRs (MFMA A/B frag)

#define B_   64
#define N_   2048
#define DIN  2
#define H_   64
#define D_   16
#define C_   66    // DIN + H
#define KI   132   // 2*C
#define KIP  160   // KI padded for K-loop (multiple of 32)
#define CB   4224  // B_*C_

#define GLD16(gp, lp) __builtin_amdgcn_global_load_lds((const __attribute__((address_space(1))) void*)(gp), (__attribute__((address_space(3))) void*)(lp), 16, 0, 0)

static __device__ __forceinline__ ushort f2bf(float v) {
  __hip_bfloat16 h = __float2bfloat16(v);
  return *(ushort*)&h;
}
static __device__ __forceinline__ float bf2f(ushort u) {
  __hip_bfloat16 h = *(__hip_bfloat16*)&u;
  return __bfloat162float(h);
}
static __device__ __forceinline__ uint packbf(float a, float b) {
  return ((uint)f2bf(b) << 16) | f2bf(a);
}

// ---------------------------------------------------------------- e = LN(node+time)*gamma+beta
__global__ void k_e(const float* __restrict__ node, const float* __restrict__ timee,
                    const float* __restrict__ g0, const float* __restrict__ b0,
                    const float* __restrict__ g1, const float* __restrict__ b1,
                    const float* __restrict__ g2, const float* __restrict__ b2,
                    float* __restrict__ e) {
  int n = blockIdx.x * blockDim.x + threadIdx.x;
  if (n >= N_) return;
  float v[D_]; float m = 0.f;
  #pragma unroll
  for (int d = 0; d < D_; ++d) { v[d] = node[n * D_ + d] + timee[d]; m += v[d]; }
  m *= (1.0f / D_);
  float var = 0.f;
  #pragma unroll
  for (int d = 0; d < D_; ++d) { float t = v[d] - m; var += t * t; }
  var *= (1.0f / D_);
  float r = rsqrtf(var + 1e-12f);
  #pragma unroll
  for (int d = 0; d < D_; ++d) {
    float y = (v[d] - m) * r;
    e[0 * N_ * D_ + n * D_ + d] = y * g0[d] + b0[d];
    e[1 * N_ * D_ + n * D_ + d] = y * g1[d] + b1[d];
    e[2 * N_ * D_ + n * D_ + d] = y * g2[d] + b2[d];
  }
}

// ---------------------------------------------------------------- S_g = e_g @ e_g^T (fp32), MFMA; gate = blockIdx.z
__global__ __launch_bounds__(256)
void k_S(const float* __restrict__ e, float* __restrict__ S) {
  __shared__ __align__(16) ushort At[128 * 32];
  __shared__ __align__(16) ushort Bt[128 * 32];
  const int t = threadIdx.x;
  const int c0 = blockIdx.x * 128, r0 = blockIdx.y * 128;
  const float* eg = e + (size_t)blockIdx.z * (N_ * D_);
  float* Sg = S + (size_t)blockIdx.z * ((size_t)N_ * N_);
  const int row = t >> 1, half = t & 1;
  {
    const float* p = eg + (size_t)(r0 + row) * D_ + half * 8;
    float4 a = *(const float4*)p, b = *(const float4*)(p + 4);
    ushort pk[8] = {f2bf(a.x), f2bf(a.y), f2bf(a.z), f2bf(a.w), f2bf(b.x), f2bf(b.y), f2bf(b.z), f2bf(b.w)};
    *(uint4*)&At[row * 32 + half * 8] = *(uint4*)pk;
    uint4 z = {0, 0, 0, 0};
    *(uint4*)&At[row * 32 + 16 + half * 8] = z;
    const float* q2 = eg + (size_t)(c0 + row) * D_ + half * 8;
    float4 c = *(const float4*)q2, d = *(const float4*)(q2 + 4);
    ushort pk2[8] = {f2bf(c.x), f2bf(c.y), f2bf(c.z), f2bf(c.w), f2bf(d.x), f2bf(d.y), f2bf(d.z), f2bf(d.w)};
    *(uint4*)&Bt[row * 32 + half * 8] = *(uint4*)pk2;
    *(uint4*)&Bt[row * 32 + 16 + half * 8] = z;
  }
  __syncthreads();
  const int l15 = t & 15, q = (t >> 4) & 3, w = t >> 6;
  const int wr = (w >> 1) * 64, wc = (w & 1) * 64;
  s8 af[4], bf[4];
  #pragma unroll
  for (int mi = 0; mi < 4; ++mi) af[mi] = *(const s8*)&At[(wr + mi * 16 + l15) * 32 + q * 8];
  #pragma unroll
  for (int ni = 0; ni < 4; ++ni) bf[ni] = *(const s8*)&Bt[(wc + ni * 16 + l15) * 32 + q * 8];
  f4 acc[4][4];
  #pragma unroll
  for (int i = 0; i < 4; ++i)
    #pragma unroll
    for (int j = 0; j < 4; ++j) acc[i][j] = (f4)0.0f;
  #pragma unroll
  for (int mi = 0; mi < 4; ++mi)
    #pragma unroll
    for (int ni = 0; ni < 4; ++ni)
      acc[mi][ni] = __builtin_amdgcn_mfma_f32_16x16x32_bf16(af[mi], bf[ni], acc[mi][ni], 0, 0, 0);
  #pragma unroll
  for (int mi = 0; mi < 4; ++mi) {
    int rr = r0 + wr + mi * 16 + q * 4;
    #pragma unroll
    for (int ni = 0; ni < 4; ++ni) {
      int cc = c0 + wc + ni * 16 + l15;
      #pragma unroll
      for (int rg = 0; rg < 4; ++rg)
        Sg[(size_t)(rr + rg) * N_ + cc] = acc[mi][ni][rg];
    }
  }
}

// ---------------------------------------------------------------- row softmax: A_g = softmax(S_g, axis=1), bf16; gate = blockIdx.z
__global__ __launch_bounds__(256)
void k_rowsm(const float* __restrict__ S, __hip_bfloat16* __restrict__ A) {
  __shared__ float red[256];
  const int r = blockIdx.x, t = threadIdx.x;
  const float* Sr = S + (size_t)blockIdx.z * ((size_t)N_ * N_) + (size_t)r * N_;
  float4 v0 = ((const float4*)Sr)[t];
  float4 v1 = ((const float4*)Sr)[t + 256];
  float mx = fmaxf(fmaxf(fmaxf(v0.x, v0.y), fmaxf(v0.z, v0.w)),
                   fmaxf(fmaxf(v1.x, v1.y), fmaxf(v1.z, v1.w)));
  red[t] = mx; __syncthreads();
  for (int st = 128; st > 0; st >>= 1) { if (t < st) red[t] = fmaxf(red[t], red[t + st]); __syncthreads(); }
  const float gmax = red[0]; __syncthreads();
  float e0 = __expf(v0.x - gmax), e1 = __expf(v0.y - gmax), e2 = __expf(v0.z - gmax), e3 = __expf(v0.w - gmax);
  float e4 = __expf(v1.x - gmax), e5 = __expf(v1.y - gmax), e6 = __expf(v1.z - gmax), e7 = __expf(v1.w - gmax);
  red[t] = e0 + e1 + e2 + e3 + e4 + e5 + e6 + e7; __syncthreads();
  for (int st = 128; st > 0; st >>= 1) { if (t < st) red[t] += red[t + st]; __syncthreads(); }
  const float inv = 1.0f / red[0];
  ushort* Ar = (ushort*)A + (size_t)blockIdx.z * ((size_t)N_ * N_) + (size_t)r * N_;
  ushort p0[4] = {f2bf(e0 * inv), f2bf(e1 * inv), f2bf(e2 * inv), f2bf(e3 * inv)};
  ushort p1[4] = {f2bf(e4 * inv), f2bf(e5 * inv), f2bf(e6 * inv), f2bf(e7 * inv)};
  *(uint2*)&Ar[t * 4] = *(uint2*)p0;
  *(uint2*)&Ar[1024 + t * 4] = *(uint2*)p1;
}

// ---------------------------------------------------------------- X^T[j=b*C+c][m] bf16 via LDS transpose
template <int MODE>  // 0: xs=[x,state]   1: cand=[x, z*state]
__global__ __launch_bounds__(256)
void k_buildX(const float* __restrict__ x, const float* __restrict__ state,
              const __hip_bfloat16* __restrict__ zbuf, __hip_bfloat16* __restrict__ XT) {
  constexpr int LDM = 72;  // row stride (shorts), 144 B: 16B-aligned rows
  __shared__ __align__(16) ushort T[C_ * LDM];
  const int t = threadIdx.x;
  const int m0 = blockIdx.x * 64, b = blockIdx.y;
  const int m = t >> 2, hq = t & 3;
  {
    const float* sp = state + ((size_t)b * N_ + m0 + m) * H_ + hq * 16;
    float sv[16];
    #pragma unroll
    for (int i = 0; i < 16; i += 4) {
      float4 v = *(const float4*)(sp + i);
      sv[i] = v.x; sv[i + 1] = v.y; sv[i + 2] = v.z; sv[i + 3] = v.w;
    }
    if (MODE) {
      const ushort* zp = (const ushort*)zbuf + ((size_t)b * N_ + m0 + m) * H_ + hq * 16;
      uint4 z0 = *(const uint4*)&zp[0], z1 = *(const uint4*)&zp[8];
      uint zw[8] = {z0.x, z0.y, z0.z, z0.w, z1.x, z1.y, z1.z, z1.w};
      #pragma unroll
      for (int i = 0; i < 8; ++i) {
        sv[2 * i]     *= bf2f((ushort)(zw[i] & 0xffffu));
        sv[2 * i + 1] *= bf2f((ushort)(zw[i] >> 16));
      }
    }
    #pragma unroll
    for (int i = 0; i < 16; ++i) T[(DIN + hq * 16 + i) * LDM + m] = f2bf(sv[i]);
    if (t < 64) {
      const float2 xv = *(const float2*)&x[((size_t)b * N_ + m0 + t) * DIN];
      T[0 * LDM + t] = f2bf(xv.x);
      T[1 * LDM + t] = f2bf(xv.y);
    }
  }
  __syncthreads();
  {
    int r = t >> 2, ch = t & 3;
    ushort* dst = (ushort*)XT + (size_t)(b * C_ + r) * N_ + m0 + ch * 16;
    *(uint4*)&dst[0] = *(uint4*)&T[r * LDM + ch * 16];
    *(uint4*)&dst[8] = *(uint4*)&T[r * LDM + ch * 16 + 8];
    if (t < 8) {
      r = 64 + (t >> 2);
      ushort* dst2 = (ushort*)XT + (size_t)(b * C_ + r) * N_ + m0 + ch * 16;
      *(uint4*)&dst2[0] = *(uint4*)&T[r * LDM + ch * 16];
      *(uint4*)&dst2[8] = *(uint4*)&T[r * LDM + ch * 16 + 8];
    }
  }
}

// ---------------------------------------------------------------- Y[r,j] = sum_m A[r,m] XT[j,m]
// Two-barrier global_load_lds staging; gate via blockIdx.z (strides in elements).
__global__ __launch_bounds__(256)
void k_gemm(const __hip_bfloat16* __restrict__ Abase, size_t astride,
            const __hip_bfloat16* __restrict__ XT,
            __hip_bfloat16* __restrict__ Ybase, size_t ystride) {
  __shared__ __align__(16) ushort At[128 * 32];
  __shared__ __align__(16) ushort Xt[128 * 32];
  const int t = threadIdx.x;
  const int j0 = blockIdx.x * 128, r0 = blockIdx.y * 128;
  const ushort* Ag = (const ushort*)Abase + (size_t)blockIdx.z * astride;
  ushort* Y = (ushort*)Ybase + (size_t)blockIdx.z * ystride;
  const int lane = t & 63, w = t >> 6;
  const int rowa = w * 32 + (lane >> 2), kc = (lane & 3) * 8;
  const ushort* gA = Ag + (size_t)(r0 + rowa) * N_ + kc;
  const ushort* gX = (const ushort*)XT + (size_t)(j0 + rowa) * N_ + kc;
  ushort* lA0 = &At[(w * 32) * 32];       // wave-uniform LDS bases; HW scatters lane*16B
  ushort* lA1 = &At[(w * 32 + 16) * 32];
  ushort* lX0 = &Xt[(w * 32) * 32];
  ushort* lX1 = &Xt[(w * 32 + 16) * 32];
  const int l15 = t & 15, q = (t >> 4) & 3;
  const int wr = (w >> 1) * 64, wc = (w & 1) * 64;
  f4 acc[4][4];
  #pragma unroll
  for (int i = 0; i < 4; ++i)
    #pragma unroll
    for (int jj = 0; jj < 4; ++jj) acc[i][jj] = (f4)0.0f;
  for (int k0 = 0; k0 < N_; k0 += 32) {
    __syncthreads();
    GLD16(gA + k0, lA0);
    GLD16(gA + 16 * N_ + k0, lA1);
    GLD16(gX + k0, lX0);
    GLD16(gX + 16 * N_ + k0, lX1);
    __syncthreads();   // compiler drains vmcnt(0) before s_barrier -> LDS data visible
    s8 af[4], bf[4];
    #pragma unroll
    for (int mi = 0; mi < 4; ++mi) af[mi] = *(const s8*)&At[(wr + mi * 16 + l15) * 32 + q * 8];
    #pragma unroll
    for (int ni = 0; ni < 4; ++ni) bf[ni] = *(const s8*)&Xt[(wc + ni * 16 + l15) * 32 + q * 8];
    #pragma unroll
    for (int mi = 0; mi < 4; ++mi)
      #pragma unroll
      for (int ni = 0; ni < 4; ++ni)
        acc[mi][ni] = __builtin_amdgcn_mfma_f32_16x16x32_bf16(af[mi], bf[ni], acc[mi][ni], 0, 0, 0);
  }
  // C/D: col = lane&15, row = quad*4 + reg  [verified m89/m91]
  // R8 FIX: store bf16 BITS via f2bf — previous `Y[..] = __float2bfloat16(v)` on ushort* Y
  // went through operator float() -> integer truncation of the value (zeroed Y silently).
  #pragma unroll
  for (int mi = 0; mi < 4; ++mi) {
    int rr = r0 + wr + mi * 16 + q * 4;
    #pragma unroll
    for (int ni = 0; ni < 4; ++ni) {
      int cc = j0 + wc + ni * 16 + l15;
      #pragma unroll
      for (int rg = 0; rg < 4; ++rg)
        Y[(size_t)(rr + rg) * CB + cc] = f2bf(acc[mi][ni][rg]);
    }
  }
}

// ---------------------------------------------------------------- Wm[n][o][KIP] bf16 = sum_d e[n,d] Wp[d,ki,o]
__global__ __launch_bounds__(256)
void k_wmat(const float* __restrict__ eg, const float* __restrict__ Wp, ushort* __restrict__ Wm) {
  constexpr int TRS = 36;  // Tr row stride (shorts)
  __shared__ float Wl[16 * 8 * 64];     // [d][kr][o]  32 KB
  __shared__ ushort Tr[8 * 64 * TRS];   // [n][o][36]
  const int t = threadIdx.x;
  const int n0 = blockIdx.x * 8;
  const int y = blockIdx.y;             // ki-quarter; y==3 covers kic 12..19 (incl. zero tail)
  const int o = t & 63, w = t >> 6;
  const int ng = w & 1, krh = (w >> 1) * 4;
  float er[4][16];
  #pragma unroll
  for (int j = 0; j < 4; ++j) {
    const float* ep = eg + (size_t)(n0 + ng * 4 + j) * D_;
    #pragma unroll
    for (int d = 0; d < D_; d += 4) {
      float4 v = *(const float4*)(ep + d);
      er[j][d] = v.x; er[j][d + 1] = v.y; er[j][d + 2] = v.z; er[j][d + 3] = v.w;
    }
  }
  const int ngroups = (y == 3) ? 2 : 1;
  for (int g = 0; g < ngroups; ++g) {
    const int kic0 = y * 4 + g * 4;
    for (int kk = 0; kk < 4; ++kk) {
      const int kic = kic0 + kk;
      __syncthreads();
      #pragma unroll
      for (int it = 0; it < 8; ++it) {
        int f = it * 256 + t;
        int d = f >> 7, rem = f & 127, kr = rem >> 4, o4 = rem & 15;
        int ki = kic * 8 + kr;
        float4 v;
        if (ki < KI) v = *(const float4*)&Wp[((size_t)d * KI + ki) * 64 + o4 * 4];
        else { v.x = 0.f; v.y = 0.f; v.z = 0.f; v.w = 0.f; }
        *(float4*)&Wl[f * 4] = v;
      }
      __syncthreads();
      float a[4][4];
      #pragma unroll
      for (int j = 0; j < 4; ++j)
        #pragma unroll
        for (int k = 0; k < 4; ++k) a[j][k] = 0.f;
      for (int d = 0; d < D_; ++d) {
        float w4[4];
        #pragma unroll
        for (int k = 0; k < 4; ++k) w4[k] = Wl[(d * 8 + krh + k) * 64 + o];
        #pragma unroll
        for (int j = 0; j < 4; ++j)
          #pragma unroll
          for (int k = 0; k < 4; ++k) a[j][k] = fmaf(er[j][d], w4[k], a[j][k]);
      }
      #pragma unroll
      for (int j = 0; j < 4; ++j) {
        ushort* tr = &Tr[((ng * 4 + j) * 64 + o) * TRS + kk * 8 + krh];
        *(uint*)&tr[0] = packbf(a[j][0], a[j][1]);
        *(uint*)&tr[2] = packbf(a[j][2], a[j][3]);
      }
    }
    __syncthreads();
    const int k0 = kic0 * 8;
    #pragma unroll
    for (int p = 0; p < 8; ++p) {
      int u = p * 256 + t;
      int nl = u >> 8, oo = (u >> 2) & 63, q = u & 3;
      const ushort* tr = &Tr[(nl * 64 + oo) * TRS + q * 8];
      uint2 lo = *(const uint2*)&tr[0];
      uint2 hi = *(const uint2*)&tr[4];
      uint4 vv; vv.x = lo.x; vv.y = lo.y; vv.z = hi.x; vv.w = hi.y;
      *(uint4*)&Wm[((size_t)(n0 + nl) * 64 + oo) * KIP + k0 + q * 8] = vv;
    }
  }
}

// ---------------------------------------------------------------- per-node einsum via MFMA; B-frags direct from global Wm
template <int MODE>  // 0: sigmoid -> bf16 gate buf ; 1: tanh + GRU combine -> fp32 d_out
__global__ __launch_bounds__(256)
void k_einsum(const float* __restrict__ e, const ushort* __restrict__ Wm, const float* __restrict__ bp,
              const __hip_bfloat16* __restrict__ Y,
              const float* __restrict__ x, const float* __restrict__ state,
              const __hip_bfloat16* __restrict__ zbuf, const __hip_bfloat16* __restrict__ rbuf,
              void* __restrict__ outp) {
  constexpr int LDK = 168;
  constexpr int LDR = 72;
  __shared__ __align__(16) ushort xg[64 * LDK];
  __shared__ __align__(16) ushort res[64 * LDR];
  __shared__ float el[D_];
  __shared__ float bl[64];
  const int n = blockIdx.x, t = threadIdx.x;
  if (t < D_) el[t] = e[n * D_ + t];
  __syncthreads();
  if (t < 64) {
    float s = 0.f;
    #pragma unroll
    for (int d = 0; d < D_; ++d) s += el[d] * bp[d * 64 + t];
    bl[t] = s;
  }
  {
    const int b = t >> 2, j = t & 3;
    const size_t bn = (size_t)b * N_ + n;
    float sv[16];
    const float* sp = state + bn * 64 + j * 16;
    #pragma unroll
    for (int i = 0; i < 16; i += 4) {
      float4 v = *(const float4*)(sp + i);
      sv[i] = v.x; sv[i + 1] = v.y; sv[i + 2] = v.z; sv[i + 3] = v.w;
    }
    if (MODE) {
      const ushort* zp = (const ushort*)zbuf + bn * 64 + j * 16;
      uint4 z0 = *(const uint4*)&zp[0], z1 = *(const uint4*)&zp[8];
      uint zw[8] = {z0.x, z0.y, z0.z, z0.w, z1.x, z1.y, z1.z, z1.w};
      #pragma unroll
      for (int i = 0; i < 8; ++i) {
        sv[2 * i]     *= bf2f((ushort)(zw[i] & 0xffffu));
        sv[2 * i + 1] *= bf2f((ushort)(zw[i] >> 16));
      }
    }
    ushort* xr = &xg[b * LDK + 2 + j * 16];
    #pragma unroll
    for (int i = 0; i < 16; i += 2) {
      uint pk = packbf(sv[i], sv[i + 1]);
      *(uint*)&xr[i] = pk;
    }
    const ushort* yp = (const ushort*)Y + (size_t)n * CB + b * C_ + j * 16;
    uint* xy = (uint*)&xg[b * LDK + 66 + j * 16];
    #pragma unroll
    for (int i = 0; i < 8; ++i) xy[i] = *(const uint*)&yp[2 * i];
    if (j == 0) *(uint*)&xg[b * LDK + 130] = *(const uint*)&yp[64];
    if (t < 64) {
      const float* xp = x + ((size_t)t * N_ + n) * DIN;
      uint pk = packbf(xp[0], xp[1]);
      *(uint*)&xg[t * LDK] = pk;
    }
    ushort* pg = &xg[b * LDK + 132 + j * 7];
    #pragma unroll
    for (int i = 0; i < 7; ++i) pg[i] = 0;
  }
  __syncthreads();
  const int l15 = t & 15, q = (t >> 4) & 3, w = t >> 6;
  const int wm = (w >> 1) * 32, wn = (w & 1) * 32;
  const ushort* Wn = Wm + (size_t)n * (64 * KIP);
  f4 acc[2][2];
  acc[0][0] = acc[0][1] = acc[1][0] = acc[1][1] = (f4)0.0f;
  #pragma unroll
  for (int kk = 0; kk < KIP; kk += 32) {
    s8 af[2], bfr[2];
    #pragma unroll
    for (int mi = 0; mi < 2; ++mi) af[mi] = *(const s8*)&xg[(wm + mi * 16 + l15) * LDK + kk + q * 8];
    #pragma unroll
    for (int ni = 0; ni < 2; ++ni) bfr[ni] = *(const s8*)(Wn + (size_t)(wn + ni * 16 + l15) * KIP + kk + q * 8);
    #pragma unroll
    for (int mi = 0; mi < 2; ++mi)
      #pragma unroll
      for (int ni = 0; ni < 2; ++ni)
        acc[mi][ni] = __builtin_amdgcn_mfma_f32_16x16x32_bf16(af[mi], bfr[ni], acc[mi][ni], 0, 0, 0);
  }
  {
    float bl0 = bl[wn + l15], bl1 = bl[wn + 16 + l15];
    #pragma unroll
    for (int mi = 0; mi < 2; ++mi)
      #pragma unroll
      for (int ni = 0; ni < 2; ++ni) {
        float bb = ni ? bl1 : bl0;
        #pragma unroll
        for (int rg = 0; rg < 4; ++rg) {
          float v = acc[mi][ni][rg] + bb;
          float a;
          if (MODE == 0) a = 1.0f / (1.0f + __expf(-v));
          else           a = 1.0f - 2.0f / (__expf(2.0f * v) + 1.0f);
          res[(wm + mi * 16 + q * 4 + rg) * LDR + (wn + ni * 16 + l15)] = f2bf(a);
        }
      }
  }
  __syncthreads();
  {
    const int b = t >> 2, j = t & 3;
    const size_t gb = ((size_t)b * N_ + n) * 64 + j * 16;
    const ushort* rr = &res[b * LDR + j * 16];
    if (MODE == 0) {
      uint4 v0 = *(const uint4*)&rr[0];
      uint4 v1 = *(const uint4*)&rr[8];
      *(uint4*)((ushort*)outp + gb) = v0;
      *(uint4*)((ushort*)outp + gb + 8) = v1;
    } else {
      float* ob = (float*)outp;
      const float* stp = state + gb;
      const ushort* rp = (const ushort*)rbuf + gb;
      uint4 r0 = *(const uint4*)&rp[0], r1 = *(const uint4*)&rp[8];
      uint rw[8] = {r0.x, r0.y, r0.z, r0.w, r1.x, r1.y, r1.z, r1.w};
      #pragma unroll
      for (int i = 0; i < 16; i += 4) {
        float4 st = *(const float4*)(stp + i);
        float4 ov;
        float rv0 = bf2f((ushort)(rw[i / 2] & 0xffffu));
        float rv1 = bf2f((ushort)(rw[i / 2] >> 16));
        float rv2 = bf2f((ushort)(rw[i / 2 + 1] & 0xffffu));
        float rv3 = bf2f((ushort)(rw[i / 2 + 1] >> 16));
        ov.x = rv0 * st.x + (1.0f - rv0) * bf2f(rr[i]);
        ov.y = rv1 * st.y + (1.0f - rv1) * bf2f(rr[i + 1]);
        ov.z = rv2 * st.z + (1.0f - rv2) * bf2f(rr[i + 2]);
        ov.w = rv3 * st.w + (1.0f - rv3) * bf2f(rr[i + 3]);
        *(float4*)(ob + gb + i) = ov;
      }
    }
  }
}

// ----------------------------------------------------------------
extern "C" void kernel_launch(void* const* d_in, const int* in_sizes, int n_in,
                              void* d_out, int out_size, void* d_ws, size_t ws_size,
                              hipStream_t stream) {
  const float* x     = (const float*)d_in[0];
  const float* state = (const float*)d_in[1];
  const float* node  = (const float*)d_in[2];
  const float* timee = (const float*)d_in[3];
  const float* W_z = (const float*)d_in[4];
  const float* b_z = (const float*)d_in[5];
  const float* g_z = (const float*)d_in[6];
  const float* be_z = (const float*)d_in[7];
  const float* W_r = (const float*)d_in[8];
  const float* b_r = (const float*)d_in[9];
  const float* g_r = (const float*)d_in[10];
  const float* be_r = (const float*)d_in[11];
  const float* W_u = (const float*)d_in[12];
  const float* b_u = (const float*)d_in[13];
  const float* g_u = (const float*)d_in[14];
  const float* be_u = (const float*)d_in[15];

  constexpr size_t NN = (size_t)N_ * N_;
  constexpr size_t ND = (size_t)N_ * D_;
  // Workspace layout (bytes):
  char* ws = (char*)d_ws;
  float*           e  = (float*)(ws);                        //       0 :    393,216
  __hip_bfloat16*  A  = (__hip_bfloat16*)(ws + 393216);      //  25,165,824
  __hip_bfloat16*  XT = (__hip_bfloat16*)(ws + 25559040);    //  17,301,504
  __hip_bfloat16*  Y  = (__hip_bfloat16*)(ws + 42860544);    //  17,301,504 (Y_z; also reused for u)
  __hip_bfloat16*  zb = (__hip_bfloat16*)(ws + 60162048);    //  16,777,216
  __hip_bfloat16*  rb = (__hip_bfloat16*)(ws + 76939264);    //  16,777,216
  float*           S  = (float*)(ws + 93716480);             // S: 1 gate (16.8 MB) small-ws / 3 gates (50.3 MB) big-ws; dead before Wm/Y_r written
  ushort*          Wm = (ushort*)(ws + 93716480);            //  41,943,040 (ends 135,659,520)
  __hip_bfloat16*  Yr = (__hip_bfloat16*)(ws + 135659520);   //  17,301,504 (big-ws only; ends 152,961,024)
  const size_t YRD = ((size_t)135659520 - 42860544) / 2;     // Y_z -> Y_r element delta
  const bool big = ws_size >= (size_t)152961024;

  float* out = (float*)d_out;

  k_e<<<8, 256, 0, stream>>>(node, timee, g_z, be_z, g_r, be_r, g_u, be_u, e);
  if (big) {
    k_S<<<dim3(16, 16, 3), 256, 0, stream>>>(e, S);
    k_rowsm<<<dim3(N_, 1, 3), 256, 0, stream>>>(S, A);
  } else {
    for (int g = 0; g < 3; ++g) {
      k_S<<<dim3(16, 16, 1), 256, 0, stream>>>(e + g * ND, S);
      k_rowsm<<<dim3(N_, 1, 1), 256, 0, stream>>>(S, A + g * NN);
    }
  }
  k_buildX<0><<<dim3(32, 64), 256, 0, stream>>>(x, state, nullptr, XT);

  dim3 ggrid1(CB / 128, N_ / 128, 1);   // 33 x 16
  dim3 ggrid2(CB / 128, N_ / 128, 2);   // fused z+r: 1056 blocks
  dim3 wgrid(N_ / 8, 4);                // 1024 blocks

  if (big) {
    k_wmat<<<wgrid, 256, 0, stream>>>(e + 0 * ND, W_z, Wm);
    k_gemm<<<ggrid2, 256, 0, stream>>>(A, NN, XT, Y, YRD);                       // z->Y, r->Yr
    k_einsum<0><<<N_, 256, 0, stream>>>(e + 0 * ND, Wm, b_z, Y, x, state, nullptr, nullptr, (void*)zb);
    k_wmat<<<wgrid, 256, 0, stream>>>(e + 1 * ND, W_r, Wm);
    k_einsum<0><<<N_, 256, 0, stream>>>(e + 1 * ND, Wm, b_r, Yr, x, state, nullptr, nullptr, (void*)rb);
  } else {
    k_wmat<<<wgrid, 256, 0, stream>>>(e + 0 * ND, W_z, Wm);
    k_gemm<<<ggrid1, 256, 0, stream>>>(A, 0, XT, Y, 0);
    k_einsum<0><<<N_, 256, 0, stream>>>(e + 0 * ND, Wm, b_z, Y, x, state, nullptr, nullptr, (void*)zb);
    k_wmat<<<wgrid, 256, 0, stream>>>(e + 1 * ND, W_r, Wm);
    k_gemm<<<ggrid1, 256, 0, stream>>>(A + NN, 0, XT, Y, 0);
    k_einsum<0><<<N_, 256, 0, stream>>>(e + 1 * ND, Wm, b_r, Y, x, state, nullptr, nullptr, (void*)rb);
  }
  // gate u: cand = [x, z*state]
  k_buildX<1><<<dim3(32, 64), 256, 0, stream>>>(x, state, zb, XT);
  k_wmat<<<wgrid, 256, 0, stream>>>(e + 2 * ND, W_u, Wm);
  k_gemm<<<ggrid1, 256, 0, stream>>>(A + 2 * NN, 0, XT, Y, 0);
  k_einsum<1><<<N_, 256, 0, stream>>>(e + 2 * ND, Wm, b_u, Y, x, state, zb, rb, (void*)out);
}